// Round 1
// baseline (1468.934 us; speedup 1.0000x reference)
//
#include <hip/hip_runtime.h>
#include <math.h>

#define CDIM 512
#define NDIM 4096
#define KDIM 64
#define BDIM 16
#define NSPLIT 8

// ---------------------------------------------------------------------------
// Shared 64x64 f32 GEMM tile core: block = 256 threads (16x16), 4x4 microtile.
// As[kk][m], Bs[kk][n]; pad 68 keeps float4 reads 16B-aligned, 2-way banks.
// ---------------------------------------------------------------------------
__device__ __forceinline__ void gemm_tile16(const float (&As)[16][68],
                                            const float (&Bs)[16][68],
                                            int ty, int tx, float (&acc)[4][4]) {
#pragma unroll
  for (int kk = 0; kk < 16; ++kk) {
    const float4 av = *reinterpret_cast<const float4*>(&As[kk][ty * 4]);
    const float4 bv = *reinterpret_cast<const float4*>(&Bs[kk][tx * 4]);
    const float a[4] = {av.x, av.y, av.z, av.w};
    const float b[4] = {bv.x, bv.y, bv.z, bv.w};
#pragma unroll
    for (int i = 0; i < 4; ++i)
#pragma unroll
      for (int j = 0; j < 4; ++j)
        acc[i][j] = fmaf(a[i], b[j], acc[i][j]);
  }
}

// ---------------------------------------------------------------------------
// conv1: xf[b,o,n] = sum_c W1[o,c] x[b,c,n] + bias[o]
// grid (N/64, C/64, B)
// ---------------------------------------------------------------------------
__global__ __launch_bounds__(256) void k_conv1(const float* __restrict__ W,
                                               const float* __restrict__ bias,
                                               const float* __restrict__ x,
                                               float* __restrict__ xf) {
  __shared__ float As[16][68];
  __shared__ float Bs[16][68];
  const int tid = threadIdx.x;
  const int tx = tid & 15, ty = tid >> 4;
  const int n0 = blockIdx.x * 64;
  const int o0 = blockIdx.y * 64;
  const int b = blockIdx.z;
  const float* xb = x + (size_t)b * CDIM * NDIM;
  float acc[4][4] = {};
  for (int c0 = 0; c0 < CDIM; c0 += 16) {
#pragma unroll
    for (int r = 0; r < 4; ++r) {  // A: W[o0+ol][c0+cl] -> As[cl][ol]
      int e = r * 256 + tid;
      int ol = e >> 4, cl = e & 15;
      As[cl][ol] = W[(size_t)(o0 + ol) * CDIM + c0 + cl];
    }
#pragma unroll
    for (int r = 0; r < 4; ++r) {  // B: x[c0+cl][n0+nl] -> Bs[cl][nl]
      int e = r * 256 + tid;
      int nl = e & 63, cl = e >> 6;
      Bs[cl][nl] = xb[(size_t)(c0 + cl) * NDIM + n0 + nl];
    }
    __syncthreads();
    gemm_tile16(As, Bs, ty, tx, acc);
    __syncthreads();
  }
  float* outb = xf + (size_t)b * CDIM * NDIM;
#pragma unroll
  for (int i = 0; i < 4; ++i) {
    int o = o0 + ty * 4 + i;
    float bv = bias[o];
    float4 v = make_float4(acc[i][0] + bv, acc[i][1] + bv, acc[i][2] + bv,
                           acc[i][3] + bv);
    *reinterpret_cast<float4*>(&outb[(size_t)o * NDIM + n0 + tx * 4]) = v;
  }
}

// ---------------------------------------------------------------------------
// init mu_b[b,c,k] = mu[c,k]
// ---------------------------------------------------------------------------
__global__ void k_init_mu(const float* __restrict__ mu, float* __restrict__ mub) {
  int idx = blockIdx.x * 256 + threadIdx.x;  // 524288 total
  mub[idx] = mu[idx & 32767];
}

// ---------------------------------------------------------------------------
// S1: logits[b,n,k] = sum_c xf[b,c,n] mu_b[b,c,k]; z = softmax_k(logits);
//     colsum[b,k] += sum_n z.   grid (N/64, B)
// ---------------------------------------------------------------------------
__global__ __launch_bounds__(256) void k_s1(const float* __restrict__ xf,
                                            const float* __restrict__ mub,
                                            float* __restrict__ z,
                                            float* __restrict__ colsum) {
  __shared__ float As[16][68];
  __shared__ float Bs[16][68];
  __shared__ float csum[64];
  const int tid = threadIdx.x;
  const int tx = tid & 15, ty = tid >> 4;
  const int n0 = blockIdx.x * 64;
  const int b = blockIdx.y;
  if (tid < 64) csum[tid] = 0.f;
  const float* xfb = xf + (size_t)b * CDIM * NDIM;
  const float* mb = mub + (size_t)b * CDIM * KDIM;
  float acc[4][4] = {};
  for (int c0 = 0; c0 < CDIM; c0 += 16) {
#pragma unroll
    for (int r = 0; r < 4; ++r) {  // A: xf[c][n] -> As[cl][nl] (rows = n)
      int e = r * 256 + tid;
      int nl = e & 63, cl = e >> 6;
      As[cl][nl] = xfb[(size_t)(c0 + cl) * NDIM + n0 + nl];
    }
#pragma unroll
    for (int r = 0; r < 4; ++r) {  // B: mu_b[c][k] -> Bs[cl][k]
      int e = r * 256 + tid;
      int k = e & 63, cl = e >> 6;
      Bs[cl][k] = mb[(size_t)(c0 + cl) * KDIM + k];
    }
    __syncthreads();
    gemm_tile16(As, Bs, ty, tx, acc);
    __syncthreads();
  }
  // softmax over k (cols). Row n = n0+ty*4+i owned by 16 lanes (tx) of one wave.
  float cp[4] = {0.f, 0.f, 0.f, 0.f};
#pragma unroll
  for (int i = 0; i < 4; ++i) {
    float m = fmaxf(fmaxf(acc[i][0], acc[i][1]), fmaxf(acc[i][2], acc[i][3]));
#pragma unroll
    for (int d = 8; d >= 1; d >>= 1) m = fmaxf(m, __shfl_xor(m, d, 16));
    float e0 = __expf(acc[i][0] - m), e1 = __expf(acc[i][1] - m);
    float e2 = __expf(acc[i][2] - m), e3 = __expf(acc[i][3] - m);
    float s = e0 + e1 + e2 + e3;
#pragma unroll
    for (int d = 8; d >= 1; d >>= 1) s += __shfl_xor(s, d, 16);
    float inv = 1.f / s;
    float4 zv = make_float4(e0 * inv, e1 * inv, e2 * inv, e3 * inv);
    int n = n0 + ty * 4 + i;
    *reinterpret_cast<float4*>(&z[((size_t)b * NDIM + n) * KDIM + tx * 4]) = zv;
    cp[0] += zv.x; cp[1] += zv.y; cp[2] += zv.z; cp[3] += zv.w;
  }
#pragma unroll
  for (int j = 0; j < 4; ++j) atomicAdd(&csum[tx * 4 + j], cp[j]);
  __syncthreads();
  if (tid < 64) atomicAdd(&colsum[b * KDIM + tid], csum[tid]);
}

// ---------------------------------------------------------------------------
// S2a: mu_part[s,b,c,k] = sum_{n in split} xf[b,c,n] * z[b,n,k]/(1e-6+colsum[b,k])
// grid (C/64, NSPLIT, B)
// ---------------------------------------------------------------------------
__global__ __launch_bounds__(256) void k_s2a(const float* __restrict__ xf,
                                             const float* __restrict__ z,
                                             const float* __restrict__ colsum,
                                             float* __restrict__ mupart) {
  __shared__ float As[16][68];
  __shared__ float Bs[16][68];
  __shared__ float scs[64];
  const int tid = threadIdx.x;
  const int tx = tid & 15, ty = tid >> 4;
  const int c0 = blockIdx.x * 64;
  const int split = blockIdx.y;
  const int b = blockIdx.z;
  if (tid < 64) scs[tid] = 1.f / (1e-6f + colsum[b * KDIM + tid]);
  __syncthreads();
  const float* xfb = xf + (size_t)b * CDIM * NDIM;
  const float* zb = z + (size_t)b * NDIM * KDIM;
  float acc[4][4] = {};
  const int nbase = split * (NDIM / NSPLIT);
  for (int nc = 0; nc < NDIM / NSPLIT; nc += 16) {
    const int n0 = nbase + nc;
#pragma unroll
    for (int r = 0; r < 4; ++r) {  // A: xf[c][n] -> As[nl][cl] (rows = c)
      int e = r * 256 + tid;
      int nl = e & 15, cl = e >> 4;
      As[nl][cl] = xfb[(size_t)(c0 + cl) * NDIM + n0 + nl];
    }
#pragma unroll
    for (int r = 0; r < 4; ++r) {  // B: z_[n][k] -> Bs[nl][k]
      int e = r * 256 + tid;
      int k = e & 63, nl = e >> 6;
      Bs[nl][k] = zb[(size_t)(n0 + nl) * KDIM + k] * scs[k];
    }
    __syncthreads();
    gemm_tile16(As, Bs, ty, tx, acc);
    __syncthreads();
  }
  float* mp = mupart + (size_t)(split * BDIM + b) * CDIM * KDIM;
#pragma unroll
  for (int i = 0; i < 4; ++i) {
    int c = c0 + ty * 4 + i;
    *reinterpret_cast<float4*>(&mp[(size_t)c * KDIM + tx * 4]) =
        make_float4(acc[i][0], acc[i][1], acc[i][2], acc[i][3]);
  }
}

// ---------------------------------------------------------------------------
// S2b1: mu_tmp = sum_s mu_part; sumsq[b,k] += sum_c mu_tmp^2. grid (C/4, B)
// ---------------------------------------------------------------------------
__global__ __launch_bounds__(256) void k_s2b1(const float* __restrict__ mupart,
                                              float* __restrict__ mutmp,
                                              float* __restrict__ sumsq) {
  __shared__ float red[64];
  const int tid = threadIdx.x;
  const int b = blockIdx.y;
  const int c = blockIdx.x * 4 + (tid >> 6);
  const int k = tid & 63;
  if (tid < 64) red[tid] = 0.f;
  __syncthreads();
  size_t idx = ((size_t)b * CDIM + c) * KDIM + k;
  float v = 0.f;
#pragma unroll
  for (int s = 0; s < NSPLIT; ++s)
    v += mupart[idx + (size_t)s * BDIM * CDIM * KDIM];
  mutmp[idx] = v;
  atomicAdd(&red[k], v * v);
  __syncthreads();
  if (tid < 64) atomicAdd(&sumsq[b * KDIM + tid], red[tid]);
}

// ---------------------------------------------------------------------------
// S2b2: mu_b = mu_tmp / (1e-6 + sqrt(sumsq))
// ---------------------------------------------------------------------------
__global__ void k_s2b2(const float* __restrict__ mutmp,
                       const float* __restrict__ sumsq,
                       float* __restrict__ mub) {
  int idx = blockIdx.x * 256 + threadIdx.x;  // 524288 total
  int b = idx >> 15;
  int k = idx & 63;
  mub[idx] = mutmp[idx] / (1e-6f + sqrtf(sumsq[b * KDIM + k]));
}

// ---------------------------------------------------------------------------
// recon[b,c,n] = relu(sum_k mu_b[b,c,k] z[b,n,k]).  grid (N/64, C/64, B)
// ---------------------------------------------------------------------------
__global__ __launch_bounds__(256) void k_recon(const float* __restrict__ mub,
                                               const float* __restrict__ z,
                                               float* __restrict__ recon) {
  __shared__ float As[16][68];
  __shared__ float Bs[16][68];
  const int tid = threadIdx.x;
  const int tx = tid & 15, ty = tid >> 4;
  const int n0 = blockIdx.x * 64;
  const int c0 = blockIdx.y * 64;
  const int b = blockIdx.z;
  const float* mb = mub + (size_t)b * CDIM * KDIM;
  const float* zb = z + (size_t)b * NDIM * KDIM;
  float acc[4][4] = {};
  for (int k0 = 0; k0 < KDIM; k0 += 16) {
#pragma unroll
    for (int r = 0; r < 4; ++r) {  // A: mu_b[c][k] -> As[kl][cl] (rows = c)
      int e = r * 256 + tid;
      int kl = e & 15, cl = e >> 4;
      As[kl][cl] = mb[(size_t)(c0 + cl) * KDIM + k0 + kl];
    }
#pragma unroll
    for (int r = 0; r < 4; ++r) {  // B: z[n][k] -> Bs[kl][nl]
      int e = r * 256 + tid;
      int kl = e & 15, nl = e >> 4;
      Bs[kl][nl] = zb[(size_t)(n0 + nl) * KDIM + k0 + kl];
    }
    __syncthreads();
    gemm_tile16(As, Bs, ty, tx, acc);
    __syncthreads();
  }
  float* rb = recon + (size_t)b * CDIM * NDIM;
#pragma unroll
  for (int i = 0; i < 4; ++i) {
    int c = c0 + ty * 4 + i;
    float4 v = make_float4(fmaxf(acc[i][0], 0.f), fmaxf(acc[i][1], 0.f),
                           fmaxf(acc[i][2], 0.f), fmaxf(acc[i][3], 0.f));
    *reinterpret_cast<float4*>(&rb[(size_t)c * NDIM + n0 + tx * 4]) = v;
  }
}

// ---------------------------------------------------------------------------
// conv2: y[b,o,n] = sum_c W2[o,c] recon[b,c,n] (no bias). grid (N/64, C/64, B)
// ---------------------------------------------------------------------------
__global__ __launch_bounds__(256) void k_conv2(const float* __restrict__ W,
                                               const float* __restrict__ recon,
                                               float* __restrict__ y) {
  __shared__ float As[16][68];
  __shared__ float Bs[16][68];
  const int tid = threadIdx.x;
  const int tx = tid & 15, ty = tid >> 4;
  const int n0 = blockIdx.x * 64;
  const int o0 = blockIdx.y * 64;
  const int b = blockIdx.z;
  const float* rb = recon + (size_t)b * CDIM * NDIM;
  float acc[4][4] = {};
  for (int c0 = 0; c0 < CDIM; c0 += 16) {
#pragma unroll
    for (int r = 0; r < 4; ++r) {
      int e = r * 256 + tid;
      int ol = e >> 4, cl = e & 15;
      As[cl][ol] = W[(size_t)(o0 + ol) * CDIM + c0 + cl];
    }
#pragma unroll
    for (int r = 0; r < 4; ++r) {
      int e = r * 256 + tid;
      int nl = e & 63, cl = e >> 6;
      Bs[cl][nl] = rb[(size_t)(c0 + cl) * NDIM + n0 + nl];
    }
    __syncthreads();
    gemm_tile16(As, Bs, ty, tx, acc);
    __syncthreads();
  }
  float* yb = y + (size_t)b * CDIM * NDIM;
#pragma unroll
  for (int i = 0; i < 4; ++i) {
    int o = o0 + ty * 4 + i;
    *reinterpret_cast<float4*>(&yb[(size_t)o * NDIM + n0 + tx * 4]) =
        make_float4(acc[i][0], acc[i][1], acc[i][2], acc[i][3]);
  }
}

// ---------------------------------------------------------------------------
// BN stats: bnsum[c] += sum_n y[b,c,n]; bnsumsq[c] += sum_n y^2. grid (C, B)
// ---------------------------------------------------------------------------
__global__ __launch_bounds__(256) void k_bnstats(const float* __restrict__ y,
                                                 float* __restrict__ bnsum,
                                                 float* __restrict__ bnsumsq) {
  const int c = blockIdx.x;
  const int b = blockIdx.y;
  const float4* row =
      reinterpret_cast<const float4*>(y + ((size_t)b * CDIM + c) * NDIM);
  float s = 0.f, q = 0.f;
#pragma unroll
  for (int i = threadIdx.x; i < NDIM / 4; i += 256) {
    float4 v = row[i];
    s += v.x + v.y + v.z + v.w;
    q += v.x * v.x + v.y * v.y + v.z * v.z + v.w * v.w;
  }
#pragma unroll
  for (int d = 32; d >= 1; d >>= 1) {
    s += __shfl_down(s, d, 64);
    q += __shfl_down(q, d, 64);
  }
  __shared__ float rs[4], rq[4];
  const int w = threadIdx.x >> 6, lane = threadIdx.x & 63;
  if (lane == 0) { rs[w] = s; rq[w] = q; }
  __syncthreads();
  if (threadIdx.x == 0) {
    atomicAdd(&bnsum[c], rs[0] + rs[1] + rs[2] + rs[3]);
    atomicAdd(&bnsumsq[c], rq[0] + rq[1] + rq[2] + rq[3]);
  }
}

// ---------------------------------------------------------------------------
// final: out = relu( (y-mean)*rsqrt(var+eps)*gamma + beta + x ), in place on y
// ---------------------------------------------------------------------------
__global__ void k_final(float* __restrict__ out, const float* __restrict__ x,
                        const float* __restrict__ bnsum,
                        const float* __restrict__ bnsumsq,
                        const float* __restrict__ gamma,
                        const float* __restrict__ beta) {
  const float invM = 1.f / (BDIM * (float)NDIM);
  const size_t total4 = (size_t)BDIM * CDIM * NDIM / 4;
  for (size_t i4 = (size_t)blockIdx.x * 256 + threadIdx.x; i4 < total4;
       i4 += (size_t)gridDim.x * 256) {
    int c = (int)((i4 >> 10) & (CDIM - 1));
    float mean = bnsum[c] * invM;
    float var = bnsumsq[c] * invM - mean * mean;
    float sc = rsqrtf(var + 1e-5f) * gamma[c];
    float sh = beta[c] - mean * sc;
    float4 yv = reinterpret_cast<const float4*>(out)[i4];
    float4 xv = reinterpret_cast<const float4*>(x)[i4];
    float4 o;
    o.x = fmaxf(fmaf(yv.x, sc, sh) + xv.x, 0.f);
    o.y = fmaxf(fmaf(yv.y, sc, sh) + xv.y, 0.f);
    o.z = fmaxf(fmaf(yv.z, sc, sh) + xv.z, 0.f);
    o.w = fmaxf(fmaf(yv.w, sc, sh) + xv.w, 0.f);
    reinterpret_cast<float4*>(out)[i4] = o;
  }
}

// ---------------------------------------------------------------------------
extern "C" void kernel_launch(void* const* d_in, const int* in_sizes, int n_in,
                              void* d_out, int out_size, void* d_ws,
                              size_t ws_size, hipStream_t stream) {
  const float* x = (const float*)d_in[0];
  const float* mu = (const float*)d_in[1];
  const float* w1 = (const float*)d_in[2];
  const float* b1 = (const float*)d_in[3];
  const float* w2 = (const float*)d_in[4];
  const float* gamma = (const float*)d_in[5];
  const float* beta = (const float*)d_in[6];
  float* out = (float*)d_out;

  float* ws = (float*)d_ws;
  float* xf = ws;                        // 33554432 (also recon later)
  float* z = xf + (size_t)33554432;      // 4194304
  float* mub = z + (size_t)4194304;      // 524288
  float* mut = mub + (size_t)524288;     // 524288
  float* mupart = mut + (size_t)524288;  // 4194304
  float* colsum = mupart + (size_t)4194304;  // 1024
  float* sumsq = colsum + 1024;              // 1024
  float* bnsum = sumsq + 1024;               // 512
  float* bnsumsq = bnsum + 512;              // 512

  k_conv1<<<dim3(NDIM / 64, CDIM / 64, BDIM), 256, 0, stream>>>(w1, b1, x, xf);
  k_init_mu<<<2048, 256, 0, stream>>>(mu, mub);

  for (int s = 0; s < 3; ++s) {
    hipMemsetAsync(colsum, 0, 2048 * sizeof(float), stream);
    k_s1<<<dim3(NDIM / 64, BDIM), 256, 0, stream>>>(xf, mub, z, colsum);
    k_s2a<<<dim3(CDIM / 64, NSPLIT, BDIM), 256, 0, stream>>>(xf, z, colsum,
                                                             mupart);
    k_s2b1<<<dim3(CDIM / 4, BDIM), 256, 0, stream>>>(mupart, mut, sumsq);
    k_s2b2<<<2048, 256, 0, stream>>>(mut, sumsq, mub);
  }

  k_recon<<<dim3(NDIM / 64, CDIM / 64, BDIM), 256, 0, stream>>>(mub, z, xf);
  k_conv2<<<dim3(NDIM / 64, CDIM / 64, BDIM), 256, 0, stream>>>(w2, xf, out);

  hipMemsetAsync(bnsum, 0, 1024 * sizeof(float), stream);
  k_bnstats<<<dim3(CDIM, BDIM), 256, 0, stream>>>(out, bnsum, bnsumsq);
  k_final<<<4096, 256, 0, stream>>>(out, x, bnsum, bnsumsq, gamma, beta);
}

// Round 2
// 792.613 us; speedup vs baseline: 1.8533x; 1.8533x over previous
//
#include <hip/hip_runtime.h>
#include <hip/hip_bf16.h>
#include <math.h>

#define CDIM 512
#define NDIM 4096
#define KDIM 64
#define BDIM 16
#define NSPLIT 8

using short8 = __attribute__((ext_vector_type(8))) short;
using f32x4  = __attribute__((ext_vector_type(4))) float;

__device__ __forceinline__ void g2lds16(const void* g, void* l) {
  __builtin_amdgcn_global_load_lds(
      (const __attribute__((address_space(1))) int*)g,
      (__attribute__((address_space(3))) int*)l, 16, 0, 0);
}

// ---------------------------------------------------------------------------
// transpose + f32->bf16: in [C][N] f32 per batch -> out [N][C] bf16 per batch
// grid (N/64, C/64, B), 256 threads
// ---------------------------------------------------------------------------
__global__ __launch_bounds__(256) void k_cvtT(const float* __restrict__ in,
                                              __hip_bfloat16* __restrict__ outT) {
  __shared__ __align__(16) __hip_bfloat16 T[64][80];
  const int t = threadIdx.x;
  const int n0 = blockIdx.x * 64, c0 = blockIdx.y * 64;
  const float* ib = in + (size_t)blockIdx.z * CDIM * NDIM;
  __hip_bfloat16* ob = outT + (size_t)blockIdx.z * NDIM * CDIM;
#pragma unroll
  for (int i = 0; i < 4; ++i) {
    int idx = i * 256 + t;
    int cl = idx >> 4, f4 = idx & 15;
    float4 v = *reinterpret_cast<const float4*>(
        &ib[(size_t)(c0 + cl) * NDIM + n0 + f4 * 4]);
    T[f4 * 4 + 0][cl] = __float2bfloat16(v.x);
    T[f4 * 4 + 1][cl] = __float2bfloat16(v.y);
    T[f4 * 4 + 2][cl] = __float2bfloat16(v.z);
    T[f4 * 4 + 3][cl] = __float2bfloat16(v.w);
  }
  __syncthreads();
#pragma unroll
  for (int i = 0; i < 2; ++i) {
    int idx = i * 256 + t;
    int nl = idx >> 3, ch = idx & 7;
    uint4 u = *reinterpret_cast<const uint4*>(&T[nl][ch * 8]);
    *reinterpret_cast<uint4*>(&ob[(size_t)(n0 + nl) * CDIM + c0 + ch * 8]) = u;
  }
}

// ---------------------------------------------------------------------------
// f32 -> bf16 elementwise (weights, same layout)
// ---------------------------------------------------------------------------
__global__ void k_cvt_w(const float* __restrict__ w,
                        __hip_bfloat16* __restrict__ wbf) {
  int i = (blockIdx.x * 256 + threadIdx.x) * 4;
  float4 v = *reinterpret_cast<const float4*>(&w[i]);
  __hip_bfloat162* o = reinterpret_cast<__hip_bfloat162*>(&wbf[i]);
  o[0] = __float22bfloat162_rn(make_float2(v.x, v.y));
  o[1] = __float22bfloat162_rn(make_float2(v.z, v.w));
}

// ---------------------------------------------------------------------------
// bf16 MFMA GEMM: out[o][n] = sum_c A[o][c] * Bt[n][c]  (+ bias[o] if hasBias)
// A: [512][512] bf16 row-major (shared across batch); Bt: per-batch [4096][512]
// 128x128 tile, BK=64, 4 waves (2x2), 16x16x32 MFMA.
// LDS linear, XOR-swizzled via pre-swizzled global source (slot ^= row&7).
// grid (N/128, M/128, B)
// ---------------------------------------------------------------------------
__global__ __launch_bounds__(256) void k_gemm(const __hip_bfloat16* __restrict__ A,
                                              const __hip_bfloat16* __restrict__ Bt,
                                              const float* __restrict__ bias,
                                              float* __restrict__ out,
                                              int hasBias) {
  __shared__ __align__(16) short At[128 * 64];
  __shared__ __align__(16) short Bs[128 * 64];
  const int tid = threadIdx.x;
  const int l = tid & 63;
  const int w = tid >> 6;
  const int wm = w >> 1, wn = w & 1;
  const int lr = l & 15, lh = l >> 4;
  const int n0 = blockIdx.x * 128;
  const int o0 = blockIdx.y * 128;
  const int b = blockIdx.z;
  const short* Ag = (const short*)A;                              // [512][512]
  const short* Bg = (const short*)Bt + (size_t)b * NDIM * CDIM;   // [4096][512]
  f32x4 acc[4][4] = {};

  for (int k0 = 0; k0 < CDIM; k0 += 64) {
#pragma unroll
    for (int i = 0; i < 4; ++i) {  // A tile: 128 rows x 64 k (8 slots of 16B)
      int slot = i * 256 + tid;
      int r = slot >> 3, s = slot & 7;
      int sp = s ^ (r & 7);
      g2lds16(Ag + (size_t)(o0 + r) * CDIM + k0 + sp * 8, At + slot * 8);
    }
#pragma unroll
    for (int i = 0; i < 4; ++i) {  // B tile
      int slot = i * 256 + tid;
      int r = slot >> 3, s = slot & 7;
      int sp = s ^ (r & 7);
      g2lds16(Bg + (size_t)(n0 + r) * CDIM + k0 + sp * 8, Bs + slot * 8);
    }
    __syncthreads();
#pragma unroll
    for (int kk = 0; kk < 2; ++kk) {
      short8 af[4], bfr[4];
#pragma unroll
      for (int m = 0; m < 4; ++m) {
        int row = wm * 64 + m * 16 + lr;
        int slot = (kk * 4 + lh) ^ (row & 7);
        af[m] = *reinterpret_cast<const short8*>(&At[row * 64 + slot * 8]);
      }
#pragma unroll
      for (int nf = 0; nf < 4; ++nf) {
        int row = wn * 64 + nf * 16 + lr;
        int slot = (kk * 4 + lh) ^ (row & 7);
        bfr[nf] = *reinterpret_cast<const short8*>(&Bs[row * 64 + slot * 8]);
      }
#pragma unroll
      for (int m = 0; m < 4; ++m)
#pragma unroll
        for (int nf = 0; nf < 4; ++nf)
          acc[m][nf] = __builtin_amdgcn_mfma_f32_16x16x32_bf16(
              af[m], bfr[nf], acc[m][nf], 0, 0, 0);
    }
    __syncthreads();
  }

  float* outb = out + (size_t)b * CDIM * NDIM;
#pragma unroll
  for (int m = 0; m < 4; ++m) {
    int ob = o0 + wm * 64 + m * 16 + lh * 4;
#pragma unroll
    for (int r = 0; r < 4; ++r) {
      float bv = hasBias ? bias[ob + r] : 0.f;
#pragma unroll
      for (int nf = 0; nf < 4; ++nf) {
        int n = n0 + wn * 64 + nf * 16 + lr;
        outb[(size_t)(ob + r) * NDIM + n] = acc[m][nf][r] + bv;
      }
    }
  }
}

// ---------------------------------------------------------------------------
// f32 64x64 GEMM tile core for the EM-loop kernels (unchanged from R1)
// ---------------------------------------------------------------------------
__device__ __forceinline__ void gemm_tile16(const float (&As)[16][68],
                                            const float (&Bs)[16][68],
                                            int ty, int tx, float (&acc)[4][4]) {
#pragma unroll
  for (int kk = 0; kk < 16; ++kk) {
    const float4 av = *reinterpret_cast<const float4*>(&As[kk][ty * 4]);
    const float4 bv = *reinterpret_cast<const float4*>(&Bs[kk][tx * 4]);
    const float a[4] = {av.x, av.y, av.z, av.w};
    const float b[4] = {bv.x, bv.y, bv.z, bv.w};
#pragma unroll
    for (int i = 0; i < 4; ++i)
#pragma unroll
      for (int j = 0; j < 4; ++j)
        acc[i][j] = fmaf(a[i], b[j], acc[i][j]);
  }
}

__global__ void k_init_mu(const float* __restrict__ mu, float* __restrict__ mub) {
  int idx = blockIdx.x * 256 + threadIdx.x;  // 524288 total
  mub[idx] = mu[idx & 32767];
}

// S1: z = softmax_k(xf^T mu); colsum[b,k] += sum_n z.  grid (N/64, B)
__global__ __launch_bounds__(256) void k_s1(const float* __restrict__ xf,
                                            const float* __restrict__ mub,
                                            float* __restrict__ z,
                                            float* __restrict__ colsum) {
  __shared__ float As[16][68];
  __shared__ float Bs[16][68];
  __shared__ float csum[64];
  const int tid = threadIdx.x;
  const int tx = tid & 15, ty = tid >> 4;
  const int n0 = blockIdx.x * 64;
  const int b = blockIdx.y;
  if (tid < 64) csum[tid] = 0.f;
  const float* xfb = xf + (size_t)b * CDIM * NDIM;
  const float* mb = mub + (size_t)b * CDIM * KDIM;
  float acc[4][4] = {};
  for (int c0 = 0; c0 < CDIM; c0 += 16) {
#pragma unroll
    for (int r = 0; r < 4; ++r) {
      int e = r * 256 + tid;
      int nl = e & 63, cl = e >> 6;
      As[cl][nl] = xfb[(size_t)(c0 + cl) * NDIM + n0 + nl];
    }
#pragma unroll
    for (int r = 0; r < 4; ++r) {
      int e = r * 256 + tid;
      int k = e & 63, cl = e >> 6;
      Bs[cl][k] = mb[(size_t)(c0 + cl) * KDIM + k];
    }
    __syncthreads();
    gemm_tile16(As, Bs, ty, tx, acc);
    __syncthreads();
  }
  float cp[4] = {0.f, 0.f, 0.f, 0.f};
#pragma unroll
  for (int i = 0; i < 4; ++i) {
    float m = fmaxf(fmaxf(acc[i][0], acc[i][1]), fmaxf(acc[i][2], acc[i][3]));
#pragma unroll
    for (int d = 8; d >= 1; d >>= 1) m = fmaxf(m, __shfl_xor(m, d, 16));
    float e0 = __expf(acc[i][0] - m), e1 = __expf(acc[i][1] - m);
    float e2 = __expf(acc[i][2] - m), e3 = __expf(acc[i][3] - m);
    float s = e0 + e1 + e2 + e3;
#pragma unroll
    for (int d = 8; d >= 1; d >>= 1) s += __shfl_xor(s, d, 16);
    float inv = 1.f / s;
    float4 zv = make_float4(e0 * inv, e1 * inv, e2 * inv, e3 * inv);
    int n = n0 + ty * 4 + i;
    *reinterpret_cast<float4*>(&z[((size_t)b * NDIM + n) * KDIM + tx * 4]) = zv;
    cp[0] += zv.x; cp[1] += zv.y; cp[2] += zv.z; cp[3] += zv.w;
  }
#pragma unroll
  for (int j = 0; j < 4; ++j) atomicAdd(&csum[tx * 4 + j], cp[j]);
  __syncthreads();
  if (tid < 64) atomicAdd(&colsum[b * KDIM + tid], csum[tid]);
}

// S2a: mu_part[s,b,c,k] = sum_{n in split} xf[c,n] z[n,k]/(1e-6+colsum[k])
__global__ __launch_bounds__(256) void k_s2a(const float* __restrict__ xf,
                                             const float* __restrict__ z,
                                             const float* __restrict__ colsum,
                                             float* __restrict__ mupart) {
  __shared__ float As[16][68];
  __shared__ float Bs[16][68];
  __shared__ float scs[64];
  const int tid = threadIdx.x;
  const int tx = tid & 15, ty = tid >> 4;
  const int c0 = blockIdx.x * 64;
  const int split = blockIdx.y;
  const int b = blockIdx.z;
  if (tid < 64) scs[tid] = 1.f / (1e-6f + colsum[b * KDIM + tid]);
  __syncthreads();
  const float* xfb = xf + (size_t)b * CDIM * NDIM;
  const float* zb = z + (size_t)b * NDIM * KDIM;
  float acc[4][4] = {};
  const int nbase = split * (NDIM / NSPLIT);
  for (int nc = 0; nc < NDIM / NSPLIT; nc += 16) {
    const int n0 = nbase + nc;
#pragma unroll
    for (int r = 0; r < 4; ++r) {
      int e = r * 256 + tid;
      int nl = e & 15, cl = e >> 4;
      As[nl][cl] = xfb[(size_t)(c0 + cl) * NDIM + n0 + nl];
    }
#pragma unroll
    for (int r = 0; r < 4; ++r) {
      int e = r * 256 + tid;
      int k = e & 63, nl = e >> 6;
      Bs[nl][k] = zb[(size_t)(n0 + nl) * KDIM + k] * scs[k];
    }
    __syncthreads();
    gemm_tile16(As, Bs, ty, tx, acc);
    __syncthreads();
  }
  float* mp = mupart + (size_t)(split * BDIM + b) * CDIM * KDIM;
#pragma unroll
  for (int i = 0; i < 4; ++i) {
    int c = c0 + ty * 4 + i;
    *reinterpret_cast<float4*>(&mp[(size_t)c * KDIM + tx * 4]) =
        make_float4(acc[i][0], acc[i][1], acc[i][2], acc[i][3]);
  }
}

__global__ __launch_bounds__(256) void k_s2b1(const float* __restrict__ mupart,
                                              float* __restrict__ mutmp,
                                              float* __restrict__ sumsq) {
  __shared__ float red[64];
  const int tid = threadIdx.x;
  const int b = blockIdx.y;
  const int c = blockIdx.x * 4 + (tid >> 6);
  const int k = tid & 63;
  if (tid < 64) red[tid] = 0.f;
  __syncthreads();
  size_t idx = ((size_t)b * CDIM + c) * KDIM + k;
  float v = 0.f;
#pragma unroll
  for (int s = 0; s < NSPLIT; ++s)
    v += mupart[idx + (size_t)s * BDIM * CDIM * KDIM];
  mutmp[idx] = v;
  atomicAdd(&red[k], v * v);
  __syncthreads();
  if (tid < 64) atomicAdd(&sumsq[b * KDIM + tid], red[tid]);
}

__global__ void k_s2b2(const float* __restrict__ mutmp,
                       const float* __restrict__ sumsq,
                       float* __restrict__ mub) {
  int idx = blockIdx.x * 256 + threadIdx.x;  // 524288 total
  int b = idx >> 15;
  int k = idx & 63;
  mub[idx] = mutmp[idx] / (1e-6f + sqrtf(sumsq[b * KDIM + k]));
}

// recon[c][n] = relu(sum_k mu_b[c,k] z[n,k])  -> f32 (into d_out scratch)
__global__ __launch_bounds__(256) void k_recon(const float* __restrict__ mub,
                                               const float* __restrict__ z,
                                               float* __restrict__ recon) {
  __shared__ float As[16][68];
  __shared__ float Bs[16][68];
  const int tid = threadIdx.x;
  const int tx = tid & 15, ty = tid >> 4;
  const int n0 = blockIdx.x * 64;
  const int c0 = blockIdx.y * 64;
  const int b = blockIdx.z;
  const float* mb = mub + (size_t)b * CDIM * KDIM;
  const float* zb = z + (size_t)b * NDIM * KDIM;
  float acc[4][4] = {};
  for (int k0 = 0; k0 < KDIM; k0 += 16) {
#pragma unroll
    for (int r = 0; r < 4; ++r) {
      int e = r * 256 + tid;
      int kl = e & 15, cl = e >> 4;
      As[kl][cl] = mb[(size_t)(c0 + cl) * KDIM + k0 + kl];
    }
#pragma unroll
    for (int r = 0; r < 4; ++r) {
      int e = r * 256 + tid;
      int kl = e & 15, nl = e >> 4;
      Bs[kl][nl] = zb[(size_t)(n0 + nl) * KDIM + k0 + kl];
    }
    __syncthreads();
    gemm_tile16(As, Bs, ty, tx, acc);
    __syncthreads();
  }
  float* rb = recon + (size_t)b * CDIM * NDIM;
#pragma unroll
  for (int i = 0; i < 4; ++i) {
    int c = c0 + ty * 4 + i;
    float4 v = make_float4(fmaxf(acc[i][0], 0.f), fmaxf(acc[i][1], 0.f),
                           fmaxf(acc[i][2], 0.f), fmaxf(acc[i][3], 0.f));
    *reinterpret_cast<float4*>(&rb[(size_t)c * NDIM + n0 + tx * 4]) = v;
  }
}

__global__ __launch_bounds__(256) void k_bnstats(const float* __restrict__ y,
                                                 float* __restrict__ bnsum,
                                                 float* __restrict__ bnsumsq) {
  const int c = blockIdx.x;
  const int b = blockIdx.y;
  const float4* row =
      reinterpret_cast<const float4*>(y + ((size_t)b * CDIM + c) * NDIM);
  float s = 0.f, q = 0.f;
#pragma unroll
  for (int i = threadIdx.x; i < NDIM / 4; i += 256) {
    float4 v = row[i];
    s += v.x + v.y + v.z + v.w;
    q += v.x * v.x + v.y * v.y + v.z * v.z + v.w * v.w;
  }
#pragma unroll
  for (int d = 32; d >= 1; d >>= 1) {
    s += __shfl_down(s, d, 64);
    q += __shfl_down(q, d, 64);
  }
  __shared__ float rs[4], rq[4];
  const int w = threadIdx.x >> 6, lane = threadIdx.x & 63;
  if (lane == 0) { rs[w] = s; rq[w] = q; }
  __syncthreads();
  if (threadIdx.x == 0) {
    atomicAdd(&bnsum[c], rs[0] + rs[1] + rs[2] + rs[3]);
    atomicAdd(&bnsumsq[c], rq[0] + rq[1] + rq[2] + rq[3]);
  }
}

__global__ void k_final(float* __restrict__ out, const float* __restrict__ x,
                        const float* __restrict__ bnsum,
                        const float* __restrict__ bnsumsq,
                        const float* __restrict__ gamma,
                        const float* __restrict__ beta) {
  const float invM = 1.f / (BDIM * (float)NDIM);
  const size_t total4 = (size_t)BDIM * CDIM * NDIM / 4;
  for (size_t i4 = (size_t)blockIdx.x * 256 + threadIdx.x; i4 < total4;
       i4 += (size_t)gridDim.x * 256) {
    int c = (int)((i4 >> 10) & (CDIM - 1));
    float mean = bnsum[c] * invM;
    float var = bnsumsq[c] * invM - mean * mean;
    float sc = rsqrtf(var + 1e-5f) * gamma[c];
    float sh = beta[c] - mean * sc;
    float4 yv = reinterpret_cast<const float4*>(out)[i4];
    float4 xv = reinterpret_cast<const float4*>(x)[i4];
    float4 o;
    o.x = fmaxf(fmaf(yv.x, sc, sh) + xv.x, 0.f);
    o.y = fmaxf(fmaf(yv.y, sc, sh) + xv.y, 0.f);
    o.z = fmaxf(fmaf(yv.z, sc, sh) + xv.z, 0.f);
    o.w = fmaxf(fmaf(yv.w, sc, sh) + xv.w, 0.f);
    reinterpret_cast<float4*>(out)[i4] = o;
  }
}

// ---------------------------------------------------------------------------
extern "C" void kernel_launch(void* const* d_in, const int* in_sizes, int n_in,
                              void* d_out, int out_size, void* d_ws,
                              size_t ws_size, hipStream_t stream) {
  const float* x = (const float*)d_in[0];
  const float* mu = (const float*)d_in[1];
  const float* w1 = (const float*)d_in[2];
  const float* b1 = (const float*)d_in[3];
  const float* w2 = (const float*)d_in[4];
  const float* gamma = (const float*)d_in[5];
  const float* beta = (const float*)d_in[6];
  float* out = (float*)d_out;
  float* xf = out;  // xf (f32) lives in d_out; dead before conv2 writes d_out

  float* ws = (float*)d_ws;
  __hip_bfloat16* bT = (__hip_bfloat16*)ws;   // 33554432 bf16 (x^T, then recon^T)
  float* z      = ws + 16777216;              // 4194304
  float* mub    = z + 4194304;                // 524288
  float* mut    = mub + 524288;               // 524288
  float* mupart = mut + 524288;               // 4194304
  __hip_bfloat16* w1bf = (__hip_bfloat16*)(mupart + 4194304);  // 131072 slots
  __hip_bfloat16* w2bf = (__hip_bfloat16*)(mupart + 4194304 + 131072);
  float* colsum  = mupart + 4194304 + 262144; // 1024
  float* sumsq   = colsum + 1024;             // 1024
  float* bnsum   = sumsq + 1024;              // 512
  float* bnsumsq = bnsum + 512;               // 512

  // bf16 conversions
  k_cvtT<<<dim3(NDIM / 64, CDIM / 64, BDIM), 256, 0, stream>>>(x, bT);
  k_cvt_w<<<CDIM * CDIM / 1024, 256, 0, stream>>>(w1, w1bf);
  k_cvt_w<<<CDIM * CDIM / 1024, 256, 0, stream>>>(w2, w2bf);

  // conv1 (bf16 MFMA): xf = W1 * x + b1   (xf in d_out)
  k_gemm<<<dim3(NDIM / 128, CDIM / 128, BDIM), 256, 0, stream>>>(w1bf, bT, b1,
                                                                 xf, 1);
  k_init_mu<<<2048, 256, 0, stream>>>(mu, mub);

  for (int s = 0; s < 3; ++s) {
    hipMemsetAsync(colsum, 0, 2048 * sizeof(float), stream);
    k_s1<<<dim3(NDIM / 64, BDIM), 256, 0, stream>>>(xf, mub, z, colsum);
    k_s2a<<<dim3(CDIM / 64, NSPLIT, BDIM), 256, 0, stream>>>(xf, z, colsum,
                                                             mupart);
    k_s2b1<<<dim3(CDIM / 4, BDIM), 256, 0, stream>>>(mupart, mut, sumsq);
    k_s2b2<<<2048, 256, 0, stream>>>(mut, sumsq, mub);
  }

  // recon (f32, into d_out; xf dead), then transpose-convert, then conv2 MFMA
  k_recon<<<dim3(NDIM / 64, CDIM / 64, BDIM), 256, 0, stream>>>(mub, z, out);
  k_cvtT<<<dim3(NDIM / 64, CDIM / 64, BDIM), 256, 0, stream>>>(out, bT);
  k_gemm<<<dim3(NDIM / 128, CDIM / 128, BDIM), 256, 0, stream>>>(w2bf, bT,
                                                                 nullptr, out, 0);

  hipMemsetAsync(bnsum, 0, 1024 * sizeof(float), stream);
  k_bnstats<<<dim3(CDIM, BDIM), 256, 0, stream>>>(out, bnsum, bnsumsq);
  k_final<<<4096, 256, 0, stream>>>(out, x, bnsum, bnsumsq, gamma, beta);
}

// Round 3
// 435.434 us; speedup vs baseline: 3.3735x; 1.8203x over previous
//
#include <hip/hip_runtime.h>
#include <math.h>

#define CDIM 512
#define NDIM 4096
#define KDIM 64
#define BDIM 16
#define NSPLIT 8

typedef __attribute__((ext_vector_type(8))) _Float16 f16x8;
typedef __attribute__((ext_vector_type(4))) float f32x4;
typedef __attribute__((ext_vector_type(8))) short short8;

__device__ __forceinline__ void g2lds16(const void* g, void* l) {
  __builtin_amdgcn_global_load_lds(
      (const __attribute__((address_space(1))) int*)g,
      (__attribute__((address_space(3))) int*)l, 16, 0, 0);
}

__device__ __forceinline__ f16x8 ldsfrag(const short* base, int row, int kk,
                                         int lh) {
  int slot = (kk * 4 + lh) ^ (row & 7);
  return *reinterpret_cast<const f16x8*>(&base[row * 64 + slot * 8]);
}

// ---------------------------------------------------------------------------
// x [b][c][n] f32 -> xT [b][n][c] fp16.  grid (N/64, C/64, B)
// ---------------------------------------------------------------------------
__global__ __launch_bounds__(256) void k_cvtT16(const float* __restrict__ in,
                                                _Float16* __restrict__ outT) {
  __shared__ __align__(16) _Float16 T[64][80];
  const int t = threadIdx.x;
  const int n0 = blockIdx.x * 64, c0 = blockIdx.y * 64;
  const float* ib = in + (size_t)blockIdx.z * CDIM * NDIM;
  _Float16* ob = outT + (size_t)blockIdx.z * NDIM * CDIM;
#pragma unroll
  for (int i = 0; i < 4; ++i) {
    int idx = i * 256 + t;
    int cl = idx >> 4, f4 = idx & 15;
    float4 v = *reinterpret_cast<const float4*>(
        &ib[(size_t)(c0 + cl) * NDIM + n0 + f4 * 4]);
    T[f4 * 4 + 0][cl] = (_Float16)v.x;
    T[f4 * 4 + 1][cl] = (_Float16)v.y;
    T[f4 * 4 + 2][cl] = (_Float16)v.z;
    T[f4 * 4 + 3][cl] = (_Float16)v.w;
  }
  __syncthreads();
#pragma unroll
  for (int i = 0; i < 2; ++i) {
    int idx = i * 256 + t;
    int nl = idx >> 3, ch = idx & 7;
    uint4 u = *reinterpret_cast<const uint4*>(&T[nl][ch * 8]);
    *reinterpret_cast<uint4*>(&ob[(size_t)(n0 + nl) * CDIM + c0 + ch * 8]) = u;
  }
}

// ---------------------------------------------------------------------------
// fp16 transpose: in [N][C] -> out [C][N] per batch.  grid (N/64, C/64, B)
// ---------------------------------------------------------------------------
__global__ __launch_bounds__(256) void k_t16(const _Float16* __restrict__ in,
                                             _Float16* __restrict__ out) {
  __shared__ __align__(16) _Float16 T[64][72];
  const int t = threadIdx.x;
  const int n0 = blockIdx.x * 64, c0 = blockIdx.y * 64;
  const _Float16* ib = in + (size_t)blockIdx.z * NDIM * CDIM;
  _Float16* ob = out + (size_t)blockIdx.z * CDIM * NDIM;
#pragma unroll
  for (int i = 0; i < 2; ++i) {
    int idx = i * 256 + t;
    int nl = idx >> 3, ch = idx & 7;
    *reinterpret_cast<uint4*>(&T[nl][ch * 8]) = *reinterpret_cast<const uint4*>(
        &ib[(size_t)(n0 + nl) * CDIM + c0 + ch * 8]);
  }
  __syncthreads();
#pragma unroll
  for (int i = 0; i < 2; ++i) {
    int idx = i * 256 + t;
    int cl = idx >> 3, nch = idx & 7;
    f16x8 v;
#pragma unroll
    for (int j = 0; j < 8; ++j) v[j] = T[nch * 8 + j][cl];
    *reinterpret_cast<f16x8*>(&ob[(size_t)(c0 + cl) * NDIM + n0 + nch * 8]) = v;
  }
}

// ---------------------------------------------------------------------------
// weights f32 -> fp16
// ---------------------------------------------------------------------------
__global__ void k_cvt_w16(const float* __restrict__ w,
                          _Float16* __restrict__ wh) {
  int i = (blockIdx.x * 256 + threadIdx.x) * 4;
  float4 v = *reinterpret_cast<const float4*>(&w[i]);
  wh[i] = (_Float16)v.x; wh[i + 1] = (_Float16)v.y;
  wh[i + 2] = (_Float16)v.z; wh[i + 3] = (_Float16)v.w;
}

// ---------------------------------------------------------------------------
// conv1: xfT[b][n][o] = (sum_c xT[n][c] w1[o][c]) + b1[o]   (fp16 out)
// grid (N/128, C/128, B); 128x128 tile, BK=64, 4 waves.
// ---------------------------------------------------------------------------
__global__ __launch_bounds__(256) void k_conv1_16(
    const _Float16* __restrict__ xT, const _Float16* __restrict__ w1,
    const float* __restrict__ b1, _Float16* __restrict__ xfT) {
  __shared__ __align__(16) short At[128 * 64];
  __shared__ __align__(16) short Bt[128 * 64];
  const int tid = threadIdx.x;
  const int l = tid & 63, w = tid >> 6;
  const int wm = w >> 1, wn = w & 1;
  const int lr = l & 15, lh = l >> 4;
  const int i0 = blockIdx.x * 128;  // n
  const int j0 = blockIdx.y * 128;  // o
  const int b = blockIdx.z;
  const short* Ag = (const short*)(xT + (size_t)b * NDIM * CDIM);
  const short* Bg = (const short*)w1;
  f32x4 acc[4][4] = {};
  for (int c0 = 0; c0 < CDIM; c0 += 64) {
#pragma unroll
    for (int i = 0; i < 4; ++i) {
      int slot = i * 256 + tid;
      int r = slot >> 3, s = slot & 7, sp = s ^ (r & 7);
      g2lds16(Ag + (size_t)(i0 + r) * CDIM + c0 + sp * 8, At + slot * 8);
    }
#pragma unroll
    for (int i = 0; i < 4; ++i) {
      int slot = i * 256 + tid;
      int r = slot >> 3, s = slot & 7, sp = s ^ (r & 7);
      g2lds16(Bg + (size_t)(j0 + r) * CDIM + c0 + sp * 8, Bt + slot * 8);
    }
    __syncthreads();
#pragma unroll
    for (int kk = 0; kk < 2; ++kk) {
      f16x8 af[4], bf[4];
#pragma unroll
      for (int m = 0; m < 4; ++m) af[m] = ldsfrag(At, wm * 64 + m * 16 + lr, kk, lh);
#pragma unroll
      for (int nf = 0; nf < 4; ++nf) bf[nf] = ldsfrag(Bt, wn * 64 + nf * 16 + lr, kk, lh);
#pragma unroll
      for (int m = 0; m < 4; ++m)
#pragma unroll
        for (int nf = 0; nf < 4; ++nf)
          acc[m][nf] = __builtin_amdgcn_mfma_f32_16x16x32_f16(af[m], bf[nf],
                                                              acc[m][nf], 0, 0, 0);
    }
    __syncthreads();
  }
  _Float16* ob = xfT + (size_t)b * NDIM * CDIM;
#pragma unroll
  for (int m = 0; m < 4; ++m) {
#pragma unroll
    for (int nf = 0; nf < 4; ++nf) {
      int j = j0 + wn * 64 + nf * 16 + lr;
      float bv = b1[j];
#pragma unroll
      for (int r = 0; r < 4; ++r) {
        int i = i0 + wm * 64 + m * 16 + lh * 4 + r;
        ob[(size_t)i * CDIM + j] = (_Float16)(acc[m][nf][r] + bv);
      }
    }
  }
}

// ---------------------------------------------------------------------------
// conv2: y[b][o][n] = sum_c w2[o][c] reconT[n][c]   (f32 out to d_out)
// grid (C/128, N/128, B)
// ---------------------------------------------------------------------------
__global__ __launch_bounds__(256) void k_conv2_16(
    const _Float16* __restrict__ w2, const _Float16* __restrict__ reconT,
    float* __restrict__ y) {
  __shared__ __align__(16) short At[128 * 64];
  __shared__ __align__(16) short Bt[128 * 64];
  const int tid = threadIdx.x;
  const int l = tid & 63, w = tid >> 6;
  const int wm = w >> 1, wn = w & 1;
  const int lr = l & 15, lh = l >> 4;
  const int i0 = blockIdx.x * 128;  // o
  const int j0 = blockIdx.y * 128;  // n
  const int b = blockIdx.z;
  const short* Ag = (const short*)w2;
  const short* Bg = (const short*)(reconT + (size_t)b * NDIM * CDIM);
  f32x4 acc[4][4] = {};
  for (int c0 = 0; c0 < CDIM; c0 += 64) {
#pragma unroll
    for (int i = 0; i < 4; ++i) {
      int slot = i * 256 + tid;
      int r = slot >> 3, s = slot & 7, sp = s ^ (r & 7);
      g2lds16(Ag + (size_t)(i0 + r) * CDIM + c0 + sp * 8, At + slot * 8);
    }
#pragma unroll
    for (int i = 0; i < 4; ++i) {
      int slot = i * 256 + tid;
      int r = slot >> 3, s = slot & 7, sp = s ^ (r & 7);
      g2lds16(Bg + (size_t)(j0 + r) * CDIM + c0 + sp * 8, Bt + slot * 8);
    }
    __syncthreads();
#pragma unroll
    for (int kk = 0; kk < 2; ++kk) {
      f16x8 af[4], bf[4];
#pragma unroll
      for (int m = 0; m < 4; ++m) af[m] = ldsfrag(At, wm * 64 + m * 16 + lr, kk, lh);
#pragma unroll
      for (int nf = 0; nf < 4; ++nf) bf[nf] = ldsfrag(Bt, wn * 64 + nf * 16 + lr, kk, lh);
#pragma unroll
      for (int m = 0; m < 4; ++m)
#pragma unroll
        for (int nf = 0; nf < 4; ++nf)
          acc[m][nf] = __builtin_amdgcn_mfma_f32_16x16x32_f16(af[m], bf[nf],
                                                              acc[m][nf], 0, 0, 0);
    }
    __syncthreads();
  }
  float* yb = y + (size_t)b * CDIM * NDIM;
#pragma unroll
  for (int m = 0; m < 4; ++m) {
#pragma unroll
    for (int r = 0; r < 4; ++r) {
      int i = i0 + wm * 64 + m * 16 + lh * 4 + r;
#pragma unroll
      for (int nf = 0; nf < 4; ++nf) {
        int j = j0 + wn * 64 + nf * 16 + lr;
        yb[(size_t)i * NDIM + j] = acc[m][nf][r];
      }
    }
  }
}

// ---------------------------------------------------------------------------
// init muT[b][k][c] fp16 = mu[c][k]
// ---------------------------------------------------------------------------
__global__ void k_init_mu16(const float* __restrict__ mu,
                            _Float16* __restrict__ muT) {
  int idx = blockIdx.x * 256 + threadIdx.x;  // 524288
  int rem = idx & 32767;
  int k = rem >> 9, c = rem & 511;
  muT[idx] = (_Float16)mu[c * KDIM + k];
}

// ---------------------------------------------------------------------------
// S1 (fp16 MFMA): logits[n][k] = sum_c xfT[n][c] muT[k][c]; z=softmax_k;
// writes z[b][n][k], zT[b][k][n] fp16, colsum[b][k] f32 atomics.
// grid (N/64, B). Tile 64n x 64k, BK=64 (8 steps), 4 waves (16n each).
// ---------------------------------------------------------------------------
__global__ __launch_bounds__(256) void k_s1_16(const _Float16* __restrict__ xfT,
                                               const _Float16* __restrict__ muT,
                                               _Float16* __restrict__ z,
                                               _Float16* __restrict__ zT,
                                               float* __restrict__ colsum) {
  __shared__ __align__(16) short At[64 * 64];
  __shared__ __align__(16) short Bt[64 * 64];
  __shared__ __align__(16) _Float16 zs[64][72];
  const int tid = threadIdx.x;
  const int l = tid & 63, w = tid >> 6;
  const int lr = l & 15, lh = l >> 4;
  const int n0 = blockIdx.x * 64;
  const int b = blockIdx.y;
  const short* Ag = (const short*)(xfT + (size_t)b * NDIM * CDIM);
  const short* Bg = (const short*)(muT + (size_t)b * KDIM * CDIM);
  f32x4 acc[4] = {};
  for (int c0 = 0; c0 < CDIM; c0 += 64) {
#pragma unroll
    for (int i = 0; i < 2; ++i) {
      int slot = i * 256 + tid;
      int r = slot >> 3, s = slot & 7, sp = s ^ (r & 7);
      g2lds16(Ag + (size_t)(n0 + r) * CDIM + c0 + sp * 8, At + slot * 8);
    }
#pragma unroll
    for (int i = 0; i < 2; ++i) {
      int slot = i * 256 + tid;
      int r = slot >> 3, s = slot & 7, sp = s ^ (r & 7);
      g2lds16(Bg + (size_t)r * CDIM + c0 + sp * 8, Bt + slot * 8);
    }
    __syncthreads();
#pragma unroll
    for (int kk = 0; kk < 2; ++kk) {
      f16x8 af = ldsfrag(At, w * 16 + lr, kk, lh);
#pragma unroll
      for (int kf = 0; kf < 4; ++kf) {
        f16x8 bf = ldsfrag(Bt, kf * 16 + lr, kk, lh);
        acc[kf] = __builtin_amdgcn_mfma_f32_16x16x32_f16(af, bf, acc[kf], 0, 0, 0);
      }
    }
    __syncthreads();
  }
  // softmax over k: per reg r, row n = w*16+lh*4+r; 64 k spread over 4 kf x 16 lr
#pragma unroll
  for (int r = 0; r < 4; ++r) {
    float m = fmaxf(fmaxf(acc[0][r], acc[1][r]), fmaxf(acc[2][r], acc[3][r]));
#pragma unroll
    for (int d = 8; d >= 1; d >>= 1) m = fmaxf(m, __shfl_xor(m, d));
    float e[4], s = 0.f;
#pragma unroll
    for (int kf = 0; kf < 4; ++kf) { e[kf] = __expf(acc[kf][r] - m); s += e[kf]; }
#pragma unroll
    for (int d = 8; d >= 1; d >>= 1) s += __shfl_xor(s, d);
    float inv = 1.f / s;
    int row = w * 16 + lh * 4 + r;
#pragma unroll
    for (int kf = 0; kf < 4; ++kf) zs[row][kf * 16 + lr] = (_Float16)(e[kf] * inv);
  }
  __syncthreads();
  _Float16* zb = z + (size_t)b * NDIM * KDIM;
  _Float16* zTb = zT + (size_t)b * KDIM * NDIM;
#pragma unroll
  for (int i = 0; i < 2; ++i) {  // z[n][k]
    int idx = i * 256 + tid;
    int n = idx >> 3, ch = idx & 7;
    *reinterpret_cast<uint4*>(&zb[(size_t)(n0 + n) * KDIM + ch * 8]) =
        *reinterpret_cast<const uint4*>(&zs[n][ch * 8]);
  }
#pragma unroll
  for (int i = 0; i < 2; ++i) {  // zT[k][n]
    int idx = i * 256 + tid;
    int k = idx >> 3, nch = idx & 7;
    f16x8 v;
#pragma unroll
    for (int j = 0; j < 8; ++j) v[j] = zs[nch * 8 + j][k];
    *reinterpret_cast<f16x8*>(&zTb[(size_t)k * NDIM + n0 + nch * 8]) = v;
  }
  if (tid < 64) {
    float s = 0.f;
#pragma unroll
    for (int n = 0; n < 64; ++n) s += (float)zs[n][tid];
    atomicAdd(&colsum[b * KDIM + tid], s);
  }
}

// ---------------------------------------------------------------------------
// S2 (fp16 MFMA): mu_part[s][b][k][c] = sum_{n in split} zT[k][n] xf[c][n]
// grid (C/64, NSPLIT, B). Tile 64k x 64c, n-chunk 512 (8 steps), 4 waves (16c).
// ---------------------------------------------------------------------------
__global__ __launch_bounds__(256) void k_s2_16(const _Float16* __restrict__ zT,
                                               const _Float16* __restrict__ xf,
                                               float* __restrict__ mupart) {
  __shared__ __align__(16) short At[64 * 64];
  __shared__ __align__(16) short Bt[64 * 64];
  const int tid = threadIdx.x;
  const int l = tid & 63, w = tid >> 6;
  const int lr = l & 15, lh = l >> 4;
  const int c0 = blockIdx.x * 64;
  const int split = blockIdx.y;
  const int b = blockIdx.z;
  const short* Ag = (const short*)(zT + (size_t)b * KDIM * NDIM);
  const short* Bg = (const short*)(xf + (size_t)b * CDIM * NDIM);
  f32x4 acc[4] = {};
  for (int st = 0; st < 8; ++st) {
    const int nb = split * (NDIM / NSPLIT) + st * 64;
#pragma unroll
    for (int i = 0; i < 2; ++i) {
      int slot = i * 256 + tid;
      int r = slot >> 3, s = slot & 7, sp = s ^ (r & 7);
      g2lds16(Ag + (size_t)r * NDIM + nb + sp * 8, At + slot * 8);
    }
#pragma unroll
    for (int i = 0; i < 2; ++i) {
      int slot = i * 256 + tid;
      int r = slot >> 3, s = slot & 7, sp = s ^ (r & 7);
      g2lds16(Bg + (size_t)(c0 + r) * NDIM + nb + sp * 8, Bt + slot * 8);
    }
    __syncthreads();
#pragma unroll
    for (int kk = 0; kk < 2; ++kk) {
      f16x8 bf = ldsfrag(Bt, w * 16 + lr, kk, lh);
#pragma unroll
      for (int kf = 0; kf < 4; ++kf) {
        f16x8 af = ldsfrag(At, kf * 16 + lr, kk, lh);
        acc[kf] = __builtin_amdgcn_mfma_f32_16x16x32_f16(af, bf, acc[kf], 0, 0, 0);
      }
    }
    __syncthreads();
  }
  float* mp = mupart + ((size_t)(split * BDIM + b) * KDIM) * CDIM;
#pragma unroll
  for (int kf = 0; kf < 4; ++kf) {
    int k = kf * 16 + lh * 4;
#pragma unroll
    for (int r = 0; r < 4; ++r)
      mp[(size_t)(k + r) * CDIM + c0 + w * 16 + lr] = acc[kf][r];
  }
}

// ---------------------------------------------------------------------------
// S2 reduce: v[c] = sum_s mu_part; t = v*scs[k]; out = t/(1e-6+|t|_2)
// writes muT[b][k][c] fp16 and mu_ck[b][c][k] fp16.  grid (K*B) blocks.
// ---------------------------------------------------------------------------
__global__ __launch_bounds__(256) void k_s2red(const float* __restrict__ mupart,
                                               const float* __restrict__ colsum,
                                               _Float16* __restrict__ muT,
                                               _Float16* __restrict__ mu_ck) {
  __shared__ float red[4];
  const int tid = threadIdx.x;
  const int b = blockIdx.x >> 6, k = blockIdx.x & 63;
  float v0 = 0.f, v1 = 0.f;
#pragma unroll
  for (int s = 0; s < NSPLIT; ++s) {
    const float* mp = mupart + ((size_t)(s * BDIM + b) * KDIM + k) * CDIM;
    v0 += mp[tid];
    v1 += mp[tid + 256];
  }
  float ssq = v0 * v0 + v1 * v1;
#pragma unroll
  for (int d = 32; d >= 1; d >>= 1) ssq += __shfl_down(ssq, d);
  if ((tid & 63) == 0) red[tid >> 6] = ssq;
  __syncthreads();
  float tot = red[0] + red[1] + red[2] + red[3];
  float scs = 1.f / (1e-6f + colsum[b * KDIM + k]);
  float inv = scs / (1e-6f + scs * sqrtf(tot));
  _Float16 o0 = (_Float16)(v0 * inv), o1 = (_Float16)(v1 * inv);
  muT[((size_t)b * KDIM + k) * CDIM + tid] = o0;
  muT[((size_t)b * KDIM + k) * CDIM + tid + 256] = o1;
  mu_ck[((size_t)b * CDIM + tid) * KDIM + k] = o0;
  mu_ck[((size_t)b * CDIM + tid + 256) * KDIM + k] = o1;
}

// ---------------------------------------------------------------------------
// recon (fp16 MFMA): reconT[n][c] = relu(sum_k z[n][k] mu_ck[c][k])
// grid (N/128, C/128, B); K=64 single stage, 4 waves 2x2.
// ---------------------------------------------------------------------------
__global__ __launch_bounds__(256) void k_recon16(const _Float16* __restrict__ z,
                                                 const _Float16* __restrict__ mu_ck,
                                                 _Float16* __restrict__ reconT) {
  __shared__ __align__(16) short Az[128 * 64];
  __shared__ __align__(16) short Bm[128 * 64];
  const int tid = threadIdx.x;
  const int l = tid & 63, w = tid >> 6;
  const int wm = w >> 1, wn = w & 1;
  const int lr = l & 15, lh = l >> 4;
  const int n0 = blockIdx.x * 128;
  const int c0 = blockIdx.y * 128;
  const int b = blockIdx.z;
  const short* Ag = (const short*)(z + (size_t)b * NDIM * KDIM);
  const short* Bg = (const short*)(mu_ck + (size_t)b * CDIM * KDIM);
#pragma unroll
  for (int i = 0; i < 4; ++i) {
    int slot = i * 256 + tid;
    int r = slot >> 3, s = slot & 7, sp = s ^ (r & 7);
    g2lds16(Ag + (size_t)(n0 + r) * KDIM + sp * 8, Az + slot * 8);
  }
#pragma unroll
  for (int i = 0; i < 4; ++i) {
    int slot = i * 256 + tid;
    int r = slot >> 3, s = slot & 7, sp = s ^ (r & 7);
    g2lds16(Bg + (size_t)(c0 + r) * KDIM + sp * 8, Bm + slot * 8);
  }
  __syncthreads();
  f32x4 acc[4][4] = {};
#pragma unroll
  for (int kk = 0; kk < 2; ++kk) {
    f16x8 af[4], bf[4];
#pragma unroll
    for (int m = 0; m < 4; ++m) af[m] = ldsfrag(Az, wm * 64 + m * 16 + lr, kk, lh);
#pragma unroll
    for (int nf = 0; nf < 4; ++nf) bf[nf] = ldsfrag(Bm, wn * 64 + nf * 16 + lr, kk, lh);
#pragma unroll
    for (int m = 0; m < 4; ++m)
#pragma unroll
      for (int nf = 0; nf < 4; ++nf)
        acc[m][nf] = __builtin_amdgcn_mfma_f32_16x16x32_f16(af[m], bf[nf],
                                                            acc[m][nf], 0, 0, 0);
  }
  _Float16* ob = reconT + (size_t)b * NDIM * CDIM;
#pragma unroll
  for (int m = 0; m < 4; ++m) {
#pragma unroll
    for (int r = 0; r < 4; ++r) {
      int n = n0 + wm * 64 + m * 16 + lh * 4 + r;
#pragma unroll
      for (int nf = 0; nf < 4; ++nf) {
        int c = c0 + wn * 64 + nf * 16 + lr;
        ob[(size_t)n * CDIM + c] = (_Float16)fmaxf(acc[m][nf][r], 0.f);
      }
    }
  }
}

// ---------------------------------------------------------------------------
// BN stats over y (d_out f32)
// ---------------------------------------------------------------------------
__global__ __launch_bounds__(256) void k_bnstats(const float* __restrict__ y,
                                                 float* __restrict__ bnsum,
                                                 float* __restrict__ bnsumsq) {
  const int c = blockIdx.x;
  const int b = blockIdx.y;
  const float4* row =
      reinterpret_cast<const float4*>(y + ((size_t)b * CDIM + c) * NDIM);
  float s = 0.f, q = 0.f;
#pragma unroll
  for (int i = threadIdx.x; i < NDIM / 4; i += 256) {
    float4 v = row[i];
    s += v.x + v.y + v.z + v.w;
    q += v.x * v.x + v.y * v.y + v.z * v.z + v.w * v.w;
  }
#pragma unroll
  for (int d = 32; d >= 1; d >>= 1) {
    s += __shfl_down(s, d);
    q += __shfl_down(q, d);
  }
  __shared__ float rs[4], rq[4];
  const int w = threadIdx.x >> 6, lane = threadIdx.x & 63;
  if (lane == 0) { rs[w] = s; rq[w] = q; }
  __syncthreads();
  if (threadIdx.x == 0) {
    atomicAdd(&bnsum[c], rs[0] + rs[1] + rs[2] + rs[3]);
    atomicAdd(&bnsumsq[c], rq[0] + rq[1] + rq[2] + rq[3]);
  }
}

__global__ void k_final(float* __restrict__ out, const float* __restrict__ x,
                        const float* __restrict__ bnsum,
                        const float* __restrict__ bnsumsq,
                        const float* __restrict__ gamma,
                        const float* __restrict__ beta) {
  const float invM = 1.f / (BDIM * (float)NDIM);
  const size_t total4 = (size_t)BDIM * CDIM * NDIM / 4;
  for (size_t i4 = (size_t)blockIdx.x * 256 + threadIdx.x; i4 < total4;
       i4 += (size_t)gridDim.x * 256) {
    int c = (int)((i4 >> 10) & (CDIM - 1));
    float mean = bnsum[c] * invM;
    float var = bnsumsq[c] * invM - mean * mean;
    float sc = rsqrtf(var + 1e-5f) * gamma[c];
    float sh = beta[c] - mean * sc;
    float4 yv = reinterpret_cast<const float4*>(out)[i4];
    float4 xv = reinterpret_cast<const float4*>(x)[i4];
    float4 o;
    o.x = fmaxf(fmaf(yv.x, sc, sh) + xv.x, 0.f);
    o.y = fmaxf(fmaf(yv.y, sc, sh) + xv.y, 0.f);
    o.z = fmaxf(fmaf(yv.z, sc, sh) + xv.z, 0.f);
    o.w = fmaxf(fmaf(yv.w, sc, sh) + xv.w, 0.f);
    reinterpret_cast<float4*>(out)[i4] = o;
  }
}

// ---------------------------------------------------------------------------
extern "C" void kernel_launch(void* const* d_in, const int* in_sizes, int n_in,
                              void* d_out, int out_size, void* d_ws,
                              size_t ws_size, hipStream_t stream) {
  const float* x = (const float*)d_in[0];
  const float* mu = (const float*)d_in[1];
  const float* w1 = (const float*)d_in[2];
  const float* b1 = (const float*)d_in[3];
  const float* w2 = (const float*)d_in[4];
  const float* gamma = (const float*)d_in[5];
  const float* beta = (const float*)d_in[6];
  float* out = (float*)d_out;

  // xf copies live in d_out until conv2 overwrites it with y.
  _Float16* xfT = (_Float16*)d_out;              // [B][N][C]
  _Float16* xf = (_Float16*)d_out + 33554432;    // [B][C][N]

  _Float16* wsH = (_Float16*)d_ws;
  _Float16* xT = wsH;                            // [B][N][C] (reused as reconT)
  _Float16* reconT = wsH;
  _Float16* z = wsH + 33554432;                  // [B][N][K]
  _Float16* zT = z + 4194304;                    // [B][K][N]
  _Float16* muT = zT + 4194304;                  // [B][K][C]
  _Float16* mu_ck = muT + 524288;                // [B][C][K]
  _Float16* w1h = mu_ck + 524288;                // [C][C]
  _Float16* w2h = w1h + 262144;
  float* wsF = (float*)(w2h + 262144);
  float* mupart = wsF;                           // [S][B][K][C] f32
  float* colsum = mupart + 4194304;              // [B][K]
  float* bnsum = colsum + 1024;                  // [C]
  float* bnsumsq = bnsum + 512;                  // [C]

  k_cvtT16<<<dim3(NDIM / 64, CDIM / 64, BDIM), 256, 0, stream>>>(x, xT);
  k_cvt_w16<<<CDIM * CDIM / 1024, 256, 0, stream>>>(w1, w1h);
  k_cvt_w16<<<CDIM * CDIM / 1024, 256, 0, stream>>>(w2, w2h);

  k_conv1_16<<<dim3(NDIM / 128, CDIM / 128, BDIM), 256, 0, stream>>>(xT, w1h,
                                                                     b1, xfT);
  k_t16<<<dim3(NDIM / 64, CDIM / 64, BDIM), 256, 0, stream>>>(xfT, xf);
  k_init_mu16<<<2048, 256, 0, stream>>>(mu, muT);

  for (int s = 0; s < 3; ++s) {
    hipMemsetAsync(colsum, 0, 1024 * sizeof(float), stream);
    k_s1_16<<<dim3(NDIM / 64, BDIM), 256, 0, stream>>>(xfT, muT, z, zT, colsum);
    k_s2_16<<<dim3(CDIM / 64, NSPLIT, BDIM), 256, 0, stream>>>(zT, xf, mupart);
    k_s2red<<<KDIM * BDIM, 256, 0, stream>>>(mupart, colsum, muT, mu_ck);
  }

  k_recon16<<<dim3(NDIM / 128, CDIM / 128, BDIM), 256, 0, stream>>>(z, mu_ck,
                                                                    reconT);
  k_conv2_16<<<dim3(CDIM / 128, NDIM / 128, BDIM), 256, 0, stream>>>(w2h, reconT,
                                                                     out);

  hipMemsetAsync(bnsum, 0, 1024 * sizeof(float), stream);
  k_bnstats<<<dim3(CDIM, BDIM), 256, 0, stream>>>(out, bnsum, bnsumsq);
  k_final<<<4096, 256, 0, stream>>>(out, x, bnsum, bnsumsq, gamma, beta);
}

// Round 4
// 396.596 us; speedup vs baseline: 3.7039x; 1.0979x over previous
//
#include <hip/hip_runtime.h>
#include <math.h>

#define CDIM 512
#define NDIM 4096
#define KDIM 64
#define BDIM 16
#define NSPLIT 8

typedef __attribute__((ext_vector_type(8))) _Float16 f16x8;
typedef __attribute__((ext_vector_type(4))) _Float16 f16x4;
typedef __attribute__((ext_vector_type(4))) float f32x4;

__device__ __forceinline__ void g2lds16(const void* g, void* l) {
  __builtin_amdgcn_global_load_lds(
      (const __attribute__((address_space(1))) int*)g,
      (__attribute__((address_space(3))) int*)l, 16, 0, 0);
}

__device__ __forceinline__ f16x8 ldsfrag(const short* base, int row, int kk,
                                         int lh) {
  int slot = (kk * 4 + lh) ^ (row & 7);
  return *reinterpret_cast<const f16x8*>(&base[row * 64 + slot * 8]);
}

// ---------------------------------------------------------------------------
// x [b][c][n] f32 -> xT [b][n][c] fp16.  grid (N/64, C/64, B)
// ---------------------------------------------------------------------------
__global__ __launch_bounds__(256) void k_cvtT16(const float* __restrict__ in,
                                                _Float16* __restrict__ outT) {
  __shared__ __align__(16) _Float16 T[64][80];
  const int t = threadIdx.x;
  const int n0 = blockIdx.x * 64, c0 = blockIdx.y * 64;
  const float* ib = in + (size_t)blockIdx.z * CDIM * NDIM;
  _Float16* ob = outT + (size_t)blockIdx.z * NDIM * CDIM;
#pragma unroll
  for (int i = 0; i < 4; ++i) {
    int idx = i * 256 + t;
    int cl = idx >> 4, f4 = idx & 15;
    float4 v = *reinterpret_cast<const float4*>(
        &ib[(size_t)(c0 + cl) * NDIM + n0 + f4 * 4]);
    T[f4 * 4 + 0][cl] = (_Float16)v.x;
    T[f4 * 4 + 1][cl] = (_Float16)v.y;
    T[f4 * 4 + 2][cl] = (_Float16)v.z;
    T[f4 * 4 + 3][cl] = (_Float16)v.w;
  }
  __syncthreads();
#pragma unroll
  for (int i = 0; i < 2; ++i) {
    int idx = i * 256 + t;
    int nl = idx >> 3, ch = idx & 7;
    uint4 u = *reinterpret_cast<const uint4*>(&T[nl][ch * 8]);
    *reinterpret_cast<uint4*>(&ob[(size_t)(n0 + nl) * CDIM + c0 + ch * 8]) = u;
  }
}

// ---------------------------------------------------------------------------
// weights f32 -> fp16
// ---------------------------------------------------------------------------
__global__ void k_cvt_w16(const float* __restrict__ w,
                          _Float16* __restrict__ wh) {
  int i = (blockIdx.x * 256 + threadIdx.x) * 4;
  float4 v = *reinterpret_cast<const float4*>(&w[i]);
  wh[i] = (_Float16)v.x; wh[i + 1] = (_Float16)v.y;
  wh[i + 2] = (_Float16)v.z; wh[i + 3] = (_Float16)v.w;
}

// ---------------------------------------------------------------------------
// conv1: xf = W1*x + b1, dual-layout output:
//   xfT[b][n][o] fp16 (scalar writes) and xf[b][o][n] fp16 (via LDS transpose)
// grid (N/128, C/128, B); 128x128 tile, BK=64, 4 waves.
// ---------------------------------------------------------------------------
__global__ __launch_bounds__(256) void k_conv1_16(
    const _Float16* __restrict__ xT, const _Float16* __restrict__ w1,
    const float* __restrict__ b1, _Float16* __restrict__ xfT,
    _Float16* __restrict__ xf) {
  __shared__ __align__(16) short smem[17408];  // At[8192] Bt[8192]; Ot overlays
  short* At = smem;
  short* Bt = smem + 8192;
  const int tid = threadIdx.x;
  const int l = tid & 63, w = tid >> 6;
  const int wm = w >> 1, wn = w & 1;
  const int lr = l & 15, lh = l >> 4;
  const int i0 = blockIdx.x * 128;  // n
  const int j0 = blockIdx.y * 128;  // o
  const int b = blockIdx.z;
  const short* Ag = (const short*)(xT + (size_t)b * NDIM * CDIM);
  const short* Bg = (const short*)w1;
  f32x4 acc[4][4] = {};
  for (int c0 = 0; c0 < CDIM; c0 += 64) {
#pragma unroll
    for (int i = 0; i < 4; ++i) {
      int slot = i * 256 + tid;
      int r = slot >> 3, s = slot & 7, sp = s ^ (r & 7);
      g2lds16(Ag + (size_t)(i0 + r) * CDIM + c0 + sp * 8, At + slot * 8);
    }
#pragma unroll
    for (int i = 0; i < 4; ++i) {
      int slot = i * 256 + tid;
      int r = slot >> 3, s = slot & 7, sp = s ^ (r & 7);
      g2lds16(Bg + (size_t)(j0 + r) * CDIM + c0 + sp * 8, Bt + slot * 8);
    }
    __syncthreads();
#pragma unroll
    for (int kk = 0; kk < 2; ++kk) {
      f16x8 af[4], bf[4];
#pragma unroll
      for (int m = 0; m < 4; ++m) af[m] = ldsfrag(At, wm * 64 + m * 16 + lr, kk, lh);
#pragma unroll
      for (int nf = 0; nf < 4; ++nf) bf[nf] = ldsfrag(Bt, wn * 64 + nf * 16 + lr, kk, lh);
#pragma unroll
      for (int m = 0; m < 4; ++m)
#pragma unroll
        for (int nf = 0; nf < 4; ++nf)
          acc[m][nf] = __builtin_amdgcn_mfma_f32_16x16x32_f16(af[m], bf[nf],
                                                              acc[m][nf], 0, 0, 0);
    }
    __syncthreads();
  }
  // Epilogue: xfT scalar writes + scatter into Ot[o][n] (pad 136)
  _Float16* Otf = (_Float16*)smem;
  _Float16* ob = xfT + (size_t)b * NDIM * CDIM;
#pragma unroll
  for (int m = 0; m < 4; ++m) {
#pragma unroll
    for (int nf = 0; nf < 4; ++nf) {
      int ol = wn * 64 + nf * 16 + lr;
      float bv = b1[j0 + ol];
#pragma unroll
      for (int r = 0; r < 4; ++r) {
        int nl = wm * 64 + m * 16 + lh * 4 + r;
        _Float16 hv = (_Float16)(acc[m][nf][r] + bv);
        ob[(size_t)(i0 + nl) * CDIM + j0 + ol] = hv;
        Otf[ol * 136 + nl] = hv;
      }
    }
  }
  __syncthreads();
  _Float16* xfb = xf + (size_t)b * CDIM * NDIM;
#pragma unroll
  for (int i = 0; i < 8; ++i) {
    int seg = i * 256 + tid;
    int row = seg >> 4, cs = seg & 15;
    f16x8 v = *reinterpret_cast<const f16x8*>(&Otf[row * 136 + cs * 8]);
    *reinterpret_cast<f16x8*>(&xfb[(size_t)(j0 + row) * NDIM + i0 + cs * 8]) = v;
  }
}

// ---------------------------------------------------------------------------
// conv2: y16[b][o][n] fp16 = sum_c w2[o][c] reconT[n][c]; fused BN partial
// stats (f32, from accumulators).  grid (C/128, N/128, B)
// ---------------------------------------------------------------------------
__global__ __launch_bounds__(256) void k_conv2_16(
    const _Float16* __restrict__ w2, const _Float16* __restrict__ reconT,
    _Float16* __restrict__ y16, float* __restrict__ bnsum,
    float* __restrict__ bnsumsq) {
  __shared__ __align__(16) short At[128 * 64];
  __shared__ __align__(16) short Bt[128 * 64];
  __shared__ float bns[128], bnq[128];
  const int tid = threadIdx.x;
  const int l = tid & 63, w = tid >> 6;
  const int wm = w >> 1, wn = w & 1;
  const int lr = l & 15, lh = l >> 4;
  const int i0 = blockIdx.x * 128;  // o
  const int j0 = blockIdx.y * 128;  // n
  const int b = blockIdx.z;
  if (tid < 128) { bns[tid] = 0.f; bnq[tid] = 0.f; }
  const short* Ag = (const short*)w2;
  const short* Bg = (const short*)(reconT + (size_t)b * NDIM * CDIM);
  f32x4 acc[4][4] = {};
  for (int c0 = 0; c0 < CDIM; c0 += 64) {
#pragma unroll
    for (int i = 0; i < 4; ++i) {
      int slot = i * 256 + tid;
      int r = slot >> 3, s = slot & 7, sp = s ^ (r & 7);
      g2lds16(Ag + (size_t)(i0 + r) * CDIM + c0 + sp * 8, At + slot * 8);
    }
#pragma unroll
    for (int i = 0; i < 4; ++i) {
      int slot = i * 256 + tid;
      int r = slot >> 3, s = slot & 7, sp = s ^ (r & 7);
      g2lds16(Bg + (size_t)(j0 + r) * CDIM + c0 + sp * 8, Bt + slot * 8);
    }
    __syncthreads();
#pragma unroll
    for (int kk = 0; kk < 2; ++kk) {
      f16x8 af[4], bf[4];
#pragma unroll
      for (int m = 0; m < 4; ++m) af[m] = ldsfrag(At, wm * 64 + m * 16 + lr, kk, lh);
#pragma unroll
      for (int nf = 0; nf < 4; ++nf) bf[nf] = ldsfrag(Bt, wn * 64 + nf * 16 + lr, kk, lh);
#pragma unroll
      for (int m = 0; m < 4; ++m)
#pragma unroll
        for (int nf = 0; nf < 4; ++nf)
          acc[m][nf] = __builtin_amdgcn_mfma_f32_16x16x32_f16(af[m], bf[nf],
                                                              acc[m][nf], 0, 0, 0);
    }
    __syncthreads();
  }
  _Float16* yb = y16 + (size_t)b * CDIM * NDIM;
#pragma unroll
  for (int m = 0; m < 4; ++m) {
#pragma unroll
    for (int r = 0; r < 4; ++r) {
      int ol = wm * 64 + m * 16 + lh * 4 + r;
      float ps = 0.f, pq = 0.f;
#pragma unroll
      for (int nf = 0; nf < 4; ++nf) {
        float v = acc[m][nf][r];
        ps += v; pq += v * v;
        yb[(size_t)(i0 + ol) * NDIM + j0 + wn * 64 + nf * 16 + lr] = (_Float16)v;
      }
#pragma unroll
      for (int d = 1; d < 16; d <<= 1) {
        ps += __shfl_xor(ps, d);
        pq += __shfl_xor(pq, d);
      }
      if (lr == 0) { atomicAdd(&bns[ol], ps); atomicAdd(&bnq[ol], pq); }
    }
  }
  __syncthreads();
  if (tid < 128) {
    atomicAdd(&bnsum[i0 + tid], bns[tid]);
    atomicAdd(&bnsumsq[i0 + tid], bnq[tid]);
  }
}

// ---------------------------------------------------------------------------
// init muT[b][k][c] fp16 = mu[c][k]
// ---------------------------------------------------------------------------
__global__ void k_init_mu16(const float* __restrict__ mu,
                            _Float16* __restrict__ muT) {
  int idx = blockIdx.x * 256 + threadIdx.x;  // 524288
  int rem = idx & 32767;
  int k = rem >> 9, c = rem & 511;
  muT[idx] = (_Float16)mu[c * KDIM + k];
}

// ---------------------------------------------------------------------------
// S1 (fp16 MFMA): logits[n][k] = sum_c xfT[n][c] muT[k][c]; z=softmax_k;
// writes z[b][n][k], zT[b][k][n] fp16, colsum[b][k] f32 atomics.
// grid (N/64, B)
// ---------------------------------------------------------------------------
__global__ __launch_bounds__(256) void k_s1_16(const _Float16* __restrict__ xfT,
                                               const _Float16* __restrict__ muT,
                                               _Float16* __restrict__ z,
                                               _Float16* __restrict__ zT,
                                               float* __restrict__ colsum) {
  __shared__ __align__(16) short At[64 * 64];
  __shared__ __align__(16) short Bt[64 * 64];
  __shared__ __align__(16) _Float16 zs[64][72];
  const int tid = threadIdx.x;
  const int l = tid & 63, w = tid >> 6;
  const int lr = l & 15, lh = l >> 4;
  const int n0 = blockIdx.x * 64;
  const int b = blockIdx.y;
  const short* Ag = (const short*)(xfT + (size_t)b * NDIM * CDIM);
  const short* Bg = (const short*)(muT + (size_t)b * KDIM * CDIM);
  f32x4 acc[4] = {};
  for (int c0 = 0; c0 < CDIM; c0 += 64) {
#pragma unroll
    for (int i = 0; i < 2; ++i) {
      int slot = i * 256 + tid;
      int r = slot >> 3, s = slot & 7, sp = s ^ (r & 7);
      g2lds16(Ag + (size_t)(n0 + r) * CDIM + c0 + sp * 8, At + slot * 8);
    }
#pragma unroll
    for (int i = 0; i < 2; ++i) {
      int slot = i * 256 + tid;
      int r = slot >> 3, s = slot & 7, sp = s ^ (r & 7);
      g2lds16(Bg + (size_t)r * CDIM + c0 + sp * 8, Bt + slot * 8);
    }
    __syncthreads();
#pragma unroll
    for (int kk = 0; kk < 2; ++kk) {
      f16x8 af = ldsfrag(At, w * 16 + lr, kk, lh);
#pragma unroll
      for (int kf = 0; kf < 4; ++kf) {
        f16x8 bf = ldsfrag(Bt, kf * 16 + lr, kk, lh);
        acc[kf] = __builtin_amdgcn_mfma_f32_16x16x32_f16(af, bf, acc[kf], 0, 0, 0);
      }
    }
    __syncthreads();
  }
#pragma unroll
  for (int r = 0; r < 4; ++r) {
    float m = fmaxf(fmaxf(acc[0][r], acc[1][r]), fmaxf(acc[2][r], acc[3][r]));
#pragma unroll
    for (int d = 8; d >= 1; d >>= 1) m = fmaxf(m, __shfl_xor(m, d));
    float e[4], s = 0.f;
#pragma unroll
    for (int kf = 0; kf < 4; ++kf) { e[kf] = __expf(acc[kf][r] - m); s += e[kf]; }
#pragma unroll
    for (int d = 8; d >= 1; d >>= 1) s += __shfl_xor(s, d);
    float inv = 1.f / s;
    int row = w * 16 + lh * 4 + r;
#pragma unroll
    for (int kf = 0; kf < 4; ++kf) zs[row][kf * 16 + lr] = (_Float16)(e[kf] * inv);
  }
  __syncthreads();
  _Float16* zb = z + (size_t)b * NDIM * KDIM;
  _Float16* zTb = zT + (size_t)b * KDIM * NDIM;
#pragma unroll
  for (int i = 0; i < 2; ++i) {  // z[n][k]
    int idx = i * 256 + tid;
    int n = idx >> 3, ch = idx & 7;
    *reinterpret_cast<uint4*>(&zb[(size_t)(n0 + n) * KDIM + ch * 8]) =
        *reinterpret_cast<const uint4*>(&zs[n][ch * 8]);
  }
#pragma unroll
  for (int i = 0; i < 2; ++i) {  // zT[k][n]
    int idx = i * 256 + tid;
    int k = idx >> 3, nch = idx & 7;
    f16x8 v;
#pragma unroll
    for (int j = 0; j < 8; ++j) v[j] = zs[nch * 8 + j][k];
    *reinterpret_cast<f16x8*>(&zTb[(size_t)k * NDIM + n0 + nch * 8]) = v;
  }
  if (tid < 64) {
    float s = 0.f;
#pragma unroll
    for (int n = 0; n < 64; ++n) s += (float)zs[n][tid];
    atomicAdd(&colsum[b * KDIM + tid], s);
  }
}

// ---------------------------------------------------------------------------
// S2 (fp16 MFMA): mu_part[s][b][k][c] = sum_{n in split} zT[k][n] xf[c][n]
// grid (C/64, NSPLIT, B)
// ---------------------------------------------------------------------------
__global__ __launch_bounds__(256) void k_s2_16(const _Float16* __restrict__ zT,
                                               const _Float16* __restrict__ xf,
                                               float* __restrict__ mupart) {
  __shared__ __align__(16) short At[64 * 64];
  __shared__ __align__(16) short Bt[64 * 64];
  const int tid = threadIdx.x;
  const int l = tid & 63, w = tid >> 6;
  const int lr = l & 15, lh = l >> 4;
  const int c0 = blockIdx.x * 64;
  const int split = blockIdx.y;
  const int b = blockIdx.z;
  const short* Ag = (const short*)(zT + (size_t)b * KDIM * NDIM);
  const short* Bg = (const short*)(xf + (size_t)b * CDIM * NDIM);
  f32x4 acc[4] = {};
  for (int st = 0; st < 8; ++st) {
    const int nb = split * (NDIM / NSPLIT) + st * 64;
#pragma unroll
    for (int i = 0; i < 2; ++i) {
      int slot = i * 256 + tid;
      int r = slot >> 3, s = slot & 7, sp = s ^ (r & 7);
      g2lds16(Ag + (size_t)r * NDIM + nb + sp * 8, At + slot * 8);
    }
#pragma unroll
    for (int i = 0; i < 2; ++i) {
      int slot = i * 256 + tid;
      int r = slot >> 3, s = slot & 7, sp = s ^ (r & 7);
      g2lds16(Bg + (size_t)(c0 + r) * NDIM + nb + sp * 8, Bt + slot * 8);
    }
    __syncthreads();
#pragma unroll
    for (int kk = 0; kk < 2; ++kk) {
      f16x8 bf = ldsfrag(Bt, w * 16 + lr, kk, lh);
#pragma unroll
      for (int kf = 0; kf < 4; ++kf) {
        f16x8 af = ldsfrag(At, kf * 16 + lr, kk, lh);
        acc[kf] = __builtin_amdgcn_mfma_f32_16x16x32_f16(af, bf, acc[kf], 0, 0, 0);
      }
    }
    __syncthreads();
  }
  float* mp = mupart + ((size_t)(split * BDIM + b) * KDIM) * CDIM;
#pragma unroll
  for (int kf = 0; kf < 4; ++kf) {
    int k = kf * 16 + lh * 4;
#pragma unroll
    for (int r = 0; r < 4; ++r)
      mp[(size_t)(k + r) * CDIM + c0 + w * 16 + lr] = acc[kf][r];
  }
}

// ---------------------------------------------------------------------------
// S2 reduce: v[c] = sum_s mu_part; t = v*scs[k]; out = t/(1e-6+|t|_2)
// ---------------------------------------------------------------------------
__global__ __launch_bounds__(256) void k_s2red(const float* __restrict__ mupart,
                                               const float* __restrict__ colsum,
                                               _Float16* __restrict__ muT,
                                               _Float16* __restrict__ mu_ck) {
  __shared__ float red[4];
  const int tid = threadIdx.x;
  const int b = blockIdx.x >> 6, k = blockIdx.x & 63;
  float v0 = 0.f, v1 = 0.f;
#pragma unroll
  for (int s = 0; s < NSPLIT; ++s) {
    const float* mp = mupart + ((size_t)(s * BDIM + b) * KDIM + k) * CDIM;
    v0 += mp[tid];
    v1 += mp[tid + 256];
  }
  float ssq = v0 * v0 + v1 * v1;
#pragma unroll
  for (int d = 32; d >= 1; d >>= 1) ssq += __shfl_down(ssq, d);
  if ((tid & 63) == 0) red[tid >> 6] = ssq;
  __syncthreads();
  float tot = red[0] + red[1] + red[2] + red[3];
  float scs = 1.f / (1e-6f + colsum[b * KDIM + k]);
  float inv = scs / (1e-6f + scs * sqrtf(tot));
  _Float16 o0 = (_Float16)(v0 * inv), o1 = (_Float16)(v1 * inv);
  muT[((size_t)b * KDIM + k) * CDIM + tid] = o0;
  muT[((size_t)b * KDIM + k) * CDIM + tid + 256] = o1;
  mu_ck[((size_t)b * CDIM + tid) * KDIM + k] = o0;
  mu_ck[((size_t)b * CDIM + tid + 256) * KDIM + k] = o1;
}

// ---------------------------------------------------------------------------
// recon (fp16 MFMA): reconT[n][c] = relu(sum_k z[n][k] mu_ck[c][k])
// grid (N/128, C/128, B)
// ---------------------------------------------------------------------------
__global__ __launch_bounds__(256) void k_recon16(const _Float16* __restrict__ z,
                                                 const _Float16* __restrict__ mu_ck,
                                                 _Float16* __restrict__ reconT) {
  __shared__ __align__(16) short Az[128 * 64];
  __shared__ __align__(16) short Bm[128 * 64];
  const int tid = threadIdx.x;
  const int l = tid & 63, w = tid >> 6;
  const int wm = w >> 1, wn = w & 1;
  const int lr = l & 15, lh = l >> 4;
  const int n0 = blockIdx.x * 128;
  const int c0 = blockIdx.y * 128;
  const int b = blockIdx.z;
  const short* Ag = (const short*)(z + (size_t)b * NDIM * KDIM);
  const short* Bg = (const short*)(mu_ck + (size_t)b * CDIM * KDIM);
#pragma unroll
  for (int i = 0; i < 4; ++i) {
    int slot = i * 256 + tid;
    int r = slot >> 3, s = slot & 7, sp = s ^ (r & 7);
    g2lds16(Ag + (size_t)(n0 + r) * KDIM + sp * 8, Az + slot * 8);
  }
#pragma unroll
  for (int i = 0; i < 4; ++i) {
    int slot = i * 256 + tid;
    int r = slot >> 3, s = slot & 7, sp = s ^ (r & 7);
    g2lds16(Bg + (size_t)(c0 + r) * KDIM + sp * 8, Bm + slot * 8);
  }
  __syncthreads();
  f32x4 acc[4][4] = {};
#pragma unroll
  for (int kk = 0; kk < 2; ++kk) {
    f16x8 af[4], bf[4];
#pragma unroll
    for (int m = 0; m < 4; ++m) af[m] = ldsfrag(Az, wm * 64 + m * 16 + lr, kk, lh);
#pragma unroll
    for (int nf = 0; nf < 4; ++nf) bf[nf] = ldsfrag(Bm, wn * 64 + nf * 16 + lr, kk, lh);
#pragma unroll
    for (int m = 0; m < 4; ++m)
#pragma unroll
      for (int nf = 0; nf < 4; ++nf)
        acc[m][nf] = __builtin_amdgcn_mfma_f32_16x16x32_f16(af[m], bf[nf],
                                                            acc[m][nf], 0, 0, 0);
  }
  _Float16* ob = reconT + (size_t)b * NDIM * CDIM;
#pragma unroll
  for (int m = 0; m < 4; ++m) {
#pragma unroll
    for (int r = 0; r < 4; ++r) {
      int n = n0 + wm * 64 + m * 16 + lh * 4 + r;
#pragma unroll
      for (int nf = 0; nf < 4; ++nf) {
        int c = c0 + wn * 64 + nf * 16 + lr;
        ob[(size_t)n * CDIM + c] = (_Float16)fmaxf(acc[m][nf][r], 0.f);
      }
    }
  }
}

// ---------------------------------------------------------------------------
// final: out = relu((y-mean)*rsqrt(var+eps)*gamma + beta + x), y fp16
// ---------------------------------------------------------------------------
__global__ void k_final(float* __restrict__ out, const _Float16* __restrict__ y16,
                        const float* __restrict__ x,
                        const float* __restrict__ bnsum,
                        const float* __restrict__ bnsumsq,
                        const float* __restrict__ gamma,
                        const float* __restrict__ beta) {
  const float invM = 1.f / (BDIM * (float)NDIM);
  const size_t total4 = (size_t)BDIM * CDIM * NDIM / 4;
  for (size_t i4 = (size_t)blockIdx.x * 256 + threadIdx.x; i4 < total4;
       i4 += (size_t)gridDim.x * 256) {
    int c = (int)((i4 >> 10) & (CDIM - 1));
    float mean = bnsum[c] * invM;
    float var = bnsumsq[c] * invM - mean * mean;
    float sc = rsqrtf(var + 1e-5f) * gamma[c];
    float sh = beta[c] - mean * sc;
    f16x4 yv = *reinterpret_cast<const f16x4*>(&y16[i4 * 4]);
    float4 xv = reinterpret_cast<const float4*>(x)[i4];
    float4 o;
    o.x = fmaxf(fmaf((float)yv[0], sc, sh) + xv.x, 0.f);
    o.y = fmaxf(fmaf((float)yv[1], sc, sh) + xv.y, 0.f);
    o.z = fmaxf(fmaf((float)yv[2], sc, sh) + xv.z, 0.f);
    o.w = fmaxf(fmaf((float)yv[3], sc, sh) + xv.w, 0.f);
    reinterpret_cast<float4*>(out)[i4] = o;
  }
}

// ---------------------------------------------------------------------------
extern "C" void kernel_launch(void* const* d_in, const int* in_sizes, int n_in,
                              void* d_out, int out_size, void* d_ws,
                              size_t ws_size, hipStream_t stream) {
  const float* x = (const float*)d_in[0];
  const float* mu = (const float*)d_in[1];
  const float* w1 = (const float*)d_in[2];
  const float* b1 = (const float*)d_in[3];
  const float* w2 = (const float*)d_in[4];
  const float* gamma = (const float*)d_in[5];
  const float* beta = (const float*)d_in[6];
  float* out = (float*)d_out;

  // xf dual copies live in d_out until conv2/final overwrite it.
  _Float16* xfT = (_Float16*)d_out;              // [B][N][C]
  _Float16* xf = (_Float16*)d_out + 33554432;    // [B][C][N]

  _Float16* wsH = (_Float16*)d_ws;
  _Float16* xT = wsH;                            // [B][N][C] (reused as reconT)
  _Float16* reconT = wsH;
  _Float16* z = wsH + 33554432;                  // [B][N][K]
  _Float16* zT = z + 4194304;                    // [B][K][N]
  _Float16* muT = zT + 4194304;                  // [B][K][C]
  _Float16* mu_ck = muT + 524288;                // [B][C][K]
  _Float16* w1h = mu_ck + 524288;                // [C][C]
  _Float16* w2h = w1h + 262144;
  float* wsF = (float*)(w2h + 262144);
  float* mupart = wsF;                           // [S][B][K][C] f32
  float* colsum = mupart + 4194304;              // [B][K]
  float* bnsum = colsum + 1024;                  // [C]
  float* bnsumsq = bnsum + 512;                  // [C]
  _Float16* y16 = (_Float16*)(bnsumsq + 512);    // [B][C][N] fp16

  k_cvtT16<<<dim3(NDIM / 64, CDIM / 64, BDIM), 256, 0, stream>>>(x, xT);
  k_cvt_w16<<<CDIM * CDIM / 1024, 256, 0, stream>>>(w1, w1h);
  k_cvt_w16<<<CDIM * CDIM / 1024, 256, 0, stream>>>(w2, w2h);

  k_conv1_16<<<dim3(NDIM / 128, CDIM / 128, BDIM), 256, 0, stream>>>(
      xT, w1h, b1, xfT, xf);
  k_init_mu16<<<2048, 256, 0, stream>>>(mu, muT);

  for (int s = 0; s < 3; ++s) {
    hipMemsetAsync(colsum, 0, 1024 * sizeof(float), stream);
    k_s1_16<<<dim3(NDIM / 64, BDIM), 256, 0, stream>>>(xfT, muT, z, zT, colsum);
    k_s2_16<<<dim3(CDIM / 64, NSPLIT, BDIM), 256, 0, stream>>>(zT, xf, mupart);
    k_s2red<<<KDIM * BDIM, 256, 0, stream>>>(mupart, colsum, muT, mu_ck);
  }

  k_recon16<<<dim3(NDIM / 128, CDIM / 128, BDIM), 256, 0, stream>>>(z, mu_ck,
                                                                    reconT);
  hipMemsetAsync(bnsum, 0, 1024 * sizeof(float), stream);
  k_conv2_16<<<dim3(CDIM / 128, NDIM / 128, BDIM), 256, 0, stream>>>(
      w2h, reconT, y16, bnsum, bnsumsq);

  k_final<<<4096, 256, 0, stream>>>(out, y16, x, bnsum, bnsumsq, gamma, beta);
}

// Round 5
// 382.419 us; speedup vs baseline: 3.8412x; 1.0371x over previous
//
#include <hip/hip_runtime.h>
#include <math.h>

#define CDIM 512
#define NDIM 4096
#define KDIM 64
#define BDIM 16
#define NSPLIT 8

typedef __attribute__((ext_vector_type(8))) _Float16 f16x8;
typedef __attribute__((ext_vector_type(4))) _Float16 f16x4;
typedef __attribute__((ext_vector_type(4))) float f32x4;

__device__ __forceinline__ void g2lds16(const void* g, void* l) {
  __builtin_amdgcn_global_load_lds(
      (const __attribute__((address_space(1))) int*)g,
      (__attribute__((address_space(3))) int*)l, 16, 0, 0);
}

__device__ __forceinline__ f16x8 ldsfrag(const short* base, int row, int kk,
                                         int lh) {
  int slot = (kk * 4 + lh) ^ (row & 7);
  return *reinterpret_cast<const f16x8*>(&base[row * 64 + slot * 8]);
}

// ---------------------------------------------------------------------------
// x [b][c][n] f32 -> xT [b][n][c] fp16.  grid (N/64, C/64, B)
// ---------------------------------------------------------------------------
__global__ __launch_bounds__(256) void k_cvtT16(const float* __restrict__ in,
                                                _Float16* __restrict__ outT) {
  __shared__ __align__(16) _Float16 T[64][80];
  const int t = threadIdx.x;
  const int n0 = blockIdx.x * 64, c0 = blockIdx.y * 64;
  const float* ib = in + (size_t)blockIdx.z * CDIM * NDIM;
  _Float16* ob = outT + (size_t)blockIdx.z * NDIM * CDIM;
#pragma unroll
  for (int i = 0; i < 4; ++i) {
    int idx = i * 256 + t;
    int cl = idx >> 4, f4 = idx & 15;
    float4 v = *reinterpret_cast<const float4*>(
        &ib[(size_t)(c0 + cl) * NDIM + n0 + f4 * 4]);
    T[f4 * 4 + 0][cl] = (_Float16)v.x;
    T[f4 * 4 + 1][cl] = (_Float16)v.y;
    T[f4 * 4 + 2][cl] = (_Float16)v.z;
    T[f4 * 4 + 3][cl] = (_Float16)v.w;
  }
  __syncthreads();
#pragma unroll
  for (int i = 0; i < 2; ++i) {
    int idx = i * 256 + t;
    int nl = idx >> 3, ch = idx & 7;
    uint4 u = *reinterpret_cast<const uint4*>(&T[nl][ch * 8]);
    *reinterpret_cast<uint4*>(&ob[(size_t)(n0 + nl) * CDIM + c0 + ch * 8]) = u;
  }
}

// ---------------------------------------------------------------------------
// weights f32 -> fp16
// ---------------------------------------------------------------------------
__global__ void k_cvt_w16(const float* __restrict__ w,
                          _Float16* __restrict__ wh) {
  int i = (blockIdx.x * 256 + threadIdx.x) * 4;
  float4 v = *reinterpret_cast<const float4*>(&w[i]);
  wh[i] = (_Float16)v.x; wh[i + 1] = (_Float16)v.y;
  wh[i + 2] = (_Float16)v.z; wh[i + 3] = (_Float16)v.w;
}

// ---------------------------------------------------------------------------
// conv1: xf = W1*x + b1, dual-layout output:
//   xfT[b][n][o] fp16 (scalar writes) and xf[b][o][n] fp16 (via LDS transpose)
// grid (N/128, C/128, B); 128x128 tile, BK=64, 4 waves.
// ---------------------------------------------------------------------------
__global__ __launch_bounds__(256) void k_conv1_16(
    const _Float16* __restrict__ xT, const _Float16* __restrict__ w1,
    const float* __restrict__ b1, _Float16* __restrict__ xfT,
    _Float16* __restrict__ xf) {
  __shared__ __align__(16) short smem[17408];  // At[8192] Bt[8192]; Ot overlays
  short* At = smem;
  short* Bt = smem + 8192;
  const int tid = threadIdx.x;
  const int l = tid & 63, w = tid >> 6;
  const int wm = w >> 1, wn = w & 1;
  const int lr = l & 15, lh = l >> 4;
  const int i0 = blockIdx.x * 128;  // n
  const int j0 = blockIdx.y * 128;  // o
  const int b = blockIdx.z;
  const short* Ag = (const short*)(xT + (size_t)b * NDIM * CDIM);
  const short* Bg = (const short*)w1;
  f32x4 acc[4][4] = {};
  for (int c0 = 0; c0 < CDIM; c0 += 64) {
#pragma unroll
    for (int i = 0; i < 4; ++i) {
      int slot = i * 256 + tid;
      int r = slot >> 3, s = slot & 7, sp = s ^ (r & 7);
      g2lds16(Ag + (size_t)(i0 + r) * CDIM + c0 + sp * 8, At + slot * 8);
    }
#pragma unroll
    for (int i = 0; i < 4; ++i) {
      int slot = i * 256 + tid;
      int r = slot >> 3, s = slot & 7, sp = s ^ (r & 7);
      g2lds16(Bg + (size_t)(j0 + r) * CDIM + c0 + sp * 8, Bt + slot * 8);
    }
    __syncthreads();
#pragma unroll
    for (int kk = 0; kk < 2; ++kk) {
      f16x8 af[4], bf[4];
#pragma unroll
      for (int m = 0; m < 4; ++m) af[m] = ldsfrag(At, wm * 64 + m * 16 + lr, kk, lh);
#pragma unroll
      for (int nf = 0; nf < 4; ++nf) bf[nf] = ldsfrag(Bt, wn * 64 + nf * 16 + lr, kk, lh);
#pragma unroll
      for (int m = 0; m < 4; ++m)
#pragma unroll
        for (int nf = 0; nf < 4; ++nf)
          acc[m][nf] = __builtin_amdgcn_mfma_f32_16x16x32_f16(af[m], bf[nf],
                                                              acc[m][nf], 0, 0, 0);
    }
    __syncthreads();
  }
  // Epilogue: xfT scalar writes + scatter into Ot[o][n] (pad 136)
  _Float16* Otf = (_Float16*)smem;
  _Float16* ob = xfT + (size_t)b * NDIM * CDIM;
#pragma unroll
  for (int m = 0; m < 4; ++m) {
#pragma unroll
    for (int nf = 0; nf < 4; ++nf) {
      int ol = wn * 64 + nf * 16 + lr;
      float bv = b1[j0 + ol];
#pragma unroll
      for (int r = 0; r < 4; ++r) {
        int nl = wm * 64 + m * 16 + lh * 4 + r;
        _Float16 hv = (_Float16)(acc[m][nf][r] + bv);
        ob[(size_t)(i0 + nl) * CDIM + j0 + ol] = hv;
        Otf[ol * 136 + nl] = hv;
      }
    }
  }
  __syncthreads();
  _Float16* xfb = xf + (size_t)b * CDIM * NDIM;
#pragma unroll
  for (int i = 0; i < 8; ++i) {
    int seg = i * 256 + tid;
    int row = seg >> 4, cs = seg & 15;
    f16x8 v = *reinterpret_cast<const f16x8*>(&Otf[row * 136 + cs * 8]);
    *reinterpret_cast<f16x8*>(&xfb[(size_t)(j0 + row) * NDIM + i0 + cs * 8]) = v;
  }
}

// ---------------------------------------------------------------------------
// conv2: y16[b][o][n] fp16 = sum_c w2[o][c] reconT[n][c]; fused BN partial
// stats.  grid (N/128, C/128, B) — n on x so blocks sharing a reconT tile
// land on the same XCD (ids differ by 32, 32%8==0).
// ---------------------------------------------------------------------------
__global__ __launch_bounds__(256) void k_conv2_16(
    const _Float16* __restrict__ w2, const _Float16* __restrict__ reconT,
    _Float16* __restrict__ y16, float* __restrict__ bnsum,
    float* __restrict__ bnsumsq) {
  __shared__ __align__(16) short At[128 * 64];
  __shared__ __align__(16) short Bt[128 * 64];
  __shared__ float bns[128], bnq[128];
  const int tid = threadIdx.x;
  const int l = tid & 63, w = tid >> 6;
  const int wm = w >> 1, wn = w & 1;
  const int lr = l & 15, lh = l >> 4;
  const int i0 = blockIdx.y * 128;  // o
  const int j0 = blockIdx.x * 128;  // n
  const int b = blockIdx.z;
  if (tid < 128) { bns[tid] = 0.f; bnq[tid] = 0.f; }
  const short* Ag = (const short*)w2;
  const short* Bg = (const short*)(reconT + (size_t)b * NDIM * CDIM);
  f32x4 acc[4][4] = {};
  for (int c0 = 0; c0 < CDIM; c0 += 64) {
#pragma unroll
    for (int i = 0; i < 4; ++i) {
      int slot = i * 256 + tid;
      int r = slot >> 3, s = slot & 7, sp = s ^ (r & 7);
      g2lds16(Ag + (size_t)(i0 + r) * CDIM + c0 + sp * 8, At + slot * 8);
    }
#pragma unroll
    for (int i = 0; i < 4; ++i) {
      int slot = i * 256 + tid;
      int r = slot >> 3, s = slot & 7, sp = s ^ (r & 7);
      g2lds16(Bg + (size_t)(j0 + r) * CDIM + c0 + sp * 8, Bt + slot * 8);
    }
    __syncthreads();
#pragma unroll
    for (int kk = 0; kk < 2; ++kk) {
      f16x8 af[4], bf[4];
#pragma unroll
      for (int m = 0; m < 4; ++m) af[m] = ldsfrag(At, wm * 64 + m * 16 + lr, kk, lh);
#pragma unroll
      for (int nf = 0; nf < 4; ++nf) bf[nf] = ldsfrag(Bt, wn * 64 + nf * 16 + lr, kk, lh);
#pragma unroll
      for (int m = 0; m < 4; ++m)
#pragma unroll
        for (int nf = 0; nf < 4; ++nf)
          acc[m][nf] = __builtin_amdgcn_mfma_f32_16x16x32_f16(af[m], bf[nf],
                                                              acc[m][nf], 0, 0, 0);
    }
    __syncthreads();
  }
  _Float16* yb = y16 + (size_t)b * CDIM * NDIM;
#pragma unroll
  for (int m = 0; m < 4; ++m) {
#pragma unroll
    for (int r = 0; r < 4; ++r) {
      int ol = wm * 64 + m * 16 + lh * 4 + r;
      float ps = 0.f, pq = 0.f;
#pragma unroll
      for (int nf = 0; nf < 4; ++nf) {
        float v = acc[m][nf][r];
        ps += v; pq += v * v;
        yb[(size_t)(i0 + ol) * NDIM + j0 + wn * 64 + nf * 16 + lr] = (_Float16)v;
      }
#pragma unroll
      for (int d = 1; d < 16; d <<= 1) {
        ps += __shfl_xor(ps, d);
        pq += __shfl_xor(pq, d);
      }
      if (lr == 0) { atomicAdd(&bns[ol], ps); atomicAdd(&bnq[ol], pq); }
    }
  }
  __syncthreads();
  if (tid < 128) {
    atomicAdd(&bnsum[i0 + tid], bns[tid]);
    atomicAdd(&bnsumsq[i0 + tid], bnq[tid]);
  }
}

// ---------------------------------------------------------------------------
// init muT[b][k][c] fp16 = mu[c][k]
// ---------------------------------------------------------------------------
__global__ void k_init_mu16(const float* __restrict__ mu,
                            _Float16* __restrict__ muT) {
  int idx = blockIdx.x * 256 + threadIdx.x;  // 524288
  int rem = idx & 32767;
  int k = rem >> 9, c = rem & 511;
  muT[idx] = (_Float16)mu[c * KDIM + k];
}

// ---------------------------------------------------------------------------
// S1 (fp16 MFMA): logits[n][k] = sum_c xfT[n][c] muT[k][c]; z=softmax_k;
// writes z[b][n][k], zT[b][k][n] fp16, colsum[b][k] f32 atomics.
// grid (N/128, B). 128n x 64k tile; 4 waves own 32 n-rows each.
// ---------------------------------------------------------------------------
__global__ __launch_bounds__(256) void k_s1_16(const _Float16* __restrict__ xfT,
                                               const _Float16* __restrict__ muT,
                                               _Float16* __restrict__ z,
                                               _Float16* __restrict__ zT,
                                               float* __restrict__ colsum) {
  __shared__ __align__(16) short At[128 * 64];
  __shared__ __align__(16) short Bt[64 * 64];
  __shared__ __align__(16) _Float16 zs[128][72];
  __shared__ float csum[4][64];
  const int tid = threadIdx.x;
  const int l = tid & 63, w = tid >> 6;
  const int lr = l & 15, lh = l >> 4;
  const int n0 = blockIdx.x * 128;
  const int b = blockIdx.y;
  const short* Ag = (const short*)(xfT + (size_t)b * NDIM * CDIM);
  const short* Bg = (const short*)(muT + (size_t)b * KDIM * CDIM);
  f32x4 acc[2][4] = {};
  for (int c0 = 0; c0 < CDIM; c0 += 64) {
#pragma unroll
    for (int i = 0; i < 4; ++i) {
      int slot = i * 256 + tid;
      int r = slot >> 3, s = slot & 7, sp = s ^ (r & 7);
      g2lds16(Ag + (size_t)(n0 + r) * CDIM + c0 + sp * 8, At + slot * 8);
    }
#pragma unroll
    for (int i = 0; i < 2; ++i) {
      int slot = i * 256 + tid;
      int r = slot >> 3, s = slot & 7, sp = s ^ (r & 7);
      g2lds16(Bg + (size_t)r * CDIM + c0 + sp * 8, Bt + slot * 8);
    }
    __syncthreads();
#pragma unroll
    for (int kk = 0; kk < 2; ++kk) {
      f16x8 af[2], bf;
#pragma unroll
      for (int nf = 0; nf < 2; ++nf)
        af[nf] = ldsfrag(At, w * 32 + nf * 16 + lr, kk, lh);
#pragma unroll
      for (int kf = 0; kf < 4; ++kf) {
        bf = ldsfrag(Bt, kf * 16 + lr, kk, lh);
#pragma unroll
        for (int nf = 0; nf < 2; ++nf)
          acc[nf][kf] = __builtin_amdgcn_mfma_f32_16x16x32_f16(af[nf], bf,
                                                               acc[nf][kf], 0, 0, 0);
      }
    }
    __syncthreads();
  }
#pragma unroll
  for (int nf = 0; nf < 2; ++nf) {
#pragma unroll
    for (int r = 0; r < 4; ++r) {
      float m = fmaxf(fmaxf(acc[nf][0][r], acc[nf][1][r]),
                      fmaxf(acc[nf][2][r], acc[nf][3][r]));
#pragma unroll
      for (int d = 8; d >= 1; d >>= 1) m = fmaxf(m, __shfl_xor(m, d));
      float e[4], s = 0.f;
#pragma unroll
      for (int kf = 0; kf < 4; ++kf) { e[kf] = __expf(acc[nf][kf][r] - m); s += e[kf]; }
#pragma unroll
      for (int d = 8; d >= 1; d >>= 1) s += __shfl_xor(s, d);
      float inv = 1.f / s;
      int row = w * 32 + nf * 16 + lh * 4 + r;
#pragma unroll
      for (int kf = 0; kf < 4; ++kf)
        zs[row][kf * 16 + lr] = (_Float16)(e[kf] * inv);
    }
  }
  __syncthreads();
  _Float16* zb = z + (size_t)b * NDIM * KDIM;
  _Float16* zTb = zT + (size_t)b * KDIM * NDIM;
#pragma unroll
  for (int i = 0; i < 4; ++i) {  // z[n][k]
    int idx = i * 256 + tid;
    int n = idx >> 3, ch = idx & 7;
    *reinterpret_cast<uint4*>(&zb[(size_t)(n0 + n) * KDIM + ch * 8]) =
        *reinterpret_cast<const uint4*>(&zs[n][ch * 8]);
  }
#pragma unroll
  for (int i = 0; i < 4; ++i) {  // zT[k][n]
    int idx = i * 256 + tid;
    int k = idx >> 4, nch = idx & 15;
    f16x8 v;
#pragma unroll
    for (int j = 0; j < 8; ++j) v[j] = zs[nch * 8 + j][k];
    *reinterpret_cast<f16x8*>(&zTb[(size_t)k * NDIM + n0 + nch * 8]) = v;
  }
  {  // colsum: thread (q=tid>>6, k=tid&63) sums 32 rows
    int k = tid & 63, q = tid >> 6;
    float s = 0.f;
#pragma unroll
    for (int n = 0; n < 32; ++n) s += (float)zs[q * 32 + n][k];
    csum[q][k] = s;
  }
  __syncthreads();
  if (tid < 64)
    atomicAdd(&colsum[b * KDIM + tid],
              csum[0][tid] + csum[1][tid] + csum[2][tid] + csum[3][tid]);
}

// ---------------------------------------------------------------------------
// S2 (fp16 MFMA): mu_part[s][b][k][c] = sum_{n in split} zT[k][n] xf[c][n]
// grid (C/128, NSPLIT, B). 64k x 128c tile; 4 waves own 32 c-cols each.
// ---------------------------------------------------------------------------
__global__ __launch_bounds__(256) void k_s2_16(const _Float16* __restrict__ zT,
                                               const _Float16* __restrict__ xf,
                                               float* __restrict__ mupart) {
  __shared__ __align__(16) short At[64 * 64];
  __shared__ __align__(16) short Bt[128 * 64];
  const int tid = threadIdx.x;
  const int l = tid & 63, w = tid >> 6;
  const int lr = l & 15, lh = l >> 4;
  const int c0 = blockIdx.x * 128;
  const int split = blockIdx.y;
  const int b = blockIdx.z;
  const short* Ag = (const short*)(zT + (size_t)b * KDIM * NDIM);
  const short* Bg = (const short*)(xf + (size_t)b * CDIM * NDIM);
  f32x4 acc[4][2] = {};
  for (int st = 0; st < 8; ++st) {
    const int nb = split * (NDIM / NSPLIT) + st * 64;
#pragma unroll
    for (int i = 0; i < 2; ++i) {
      int slot = i * 256 + tid;
      int r = slot >> 3, s = slot & 7, sp = s ^ (r & 7);
      g2lds16(Ag + (size_t)r * NDIM + nb + sp * 8, At + slot * 8);
    }
#pragma unroll
    for (int i = 0; i < 4; ++i) {
      int slot = i * 256 + tid;
      int r = slot >> 3, s = slot & 7, sp = s ^ (r & 7);
      g2lds16(Bg + (size_t)(c0 + r) * NDIM + nb + sp * 8, Bt + slot * 8);
    }
    __syncthreads();
#pragma unroll
    for (int kk = 0; kk < 2; ++kk) {
      f16x8 bf[2], af;
#pragma unroll
      for (int cf = 0; cf < 2; ++cf)
        bf[cf] = ldsfrag(Bt, w * 32 + cf * 16 + lr, kk, lh);
#pragma unroll
      for (int kf = 0; kf < 4; ++kf) {
        af = ldsfrag(At, kf * 16 + lr, kk, lh);
#pragma unroll
        for (int cf = 0; cf < 2; ++cf)
          acc[kf][cf] = __builtin_amdgcn_mfma_f32_16x16x32_f16(af, bf[cf],
                                                               acc[kf][cf], 0, 0, 0);
      }
    }
    __syncthreads();
  }
  float* mp = mupart + ((size_t)(split * BDIM + b) * KDIM) * CDIM;
#pragma unroll
  for (int kf = 0; kf < 4; ++kf) {
    int k = kf * 16 + lh * 4;
#pragma unroll
    for (int r = 0; r < 4; ++r)
#pragma unroll
      for (int cf = 0; cf < 2; ++cf)
        mp[(size_t)(k + r) * CDIM + c0 + w * 32 + cf * 16 + lr] = acc[kf][cf][r];
  }
}

// ---------------------------------------------------------------------------
// S2 reduce: v[c] = sum_s mu_part; t = v*scs[k]; out = t/(1e-6+|t|_2)
// ---------------------------------------------------------------------------
__global__ __launch_bounds__(256) void k_s2red(const float* __restrict__ mupart,
                                               const float* __restrict__ colsum,
                                               _Float16* __restrict__ muT,
                                               _Float16* __restrict__ mu_ck) {
  __shared__ float red[4];
  const int tid = threadIdx.x;
  const int b = blockIdx.x >> 6, k = blockIdx.x & 63;
  float v0 = 0.f, v1 = 0.f;
#pragma unroll
  for (int s = 0; s < NSPLIT; ++s) {
    const float* mp = mupart + ((size_t)(s * BDIM + b) * KDIM + k) * CDIM;
    v0 += mp[tid];
    v1 += mp[tid + 256];
  }
  float ssq = v0 * v0 + v1 * v1;
#pragma unroll
  for (int d = 32; d >= 1; d >>= 1) ssq += __shfl_down(ssq, d);
  if ((tid & 63) == 0) red[tid >> 6] = ssq;
  __syncthreads();
  float tot = red[0] + red[1] + red[2] + red[3];
  float scs = 1.f / (1e-6f + colsum[b * KDIM + k]);
  float inv = scs / (1e-6f + scs * sqrtf(tot));
  _Float16 o0 = (_Float16)(v0 * inv), o1 = (_Float16)(v1 * inv);
  muT[((size_t)b * KDIM + k) * CDIM + tid] = o0;
  muT[((size_t)b * KDIM + k) * CDIM + tid + 256] = o1;
  mu_ck[((size_t)b * CDIM + tid) * KDIM + k] = o0;
  mu_ck[((size_t)b * CDIM + tid + 256) * KDIM + k] = o1;
}

// ---------------------------------------------------------------------------
// recon (fp16 MFMA): reconT[n][c] = relu(sum_k z[n][k] mu_ck[c][k])
// grid (N/128, C/128, B)
// ---------------------------------------------------------------------------
__global__ __launch_bounds__(256) void k_recon16(const _Float16* __restrict__ z,
                                                 const _Float16* __restrict__ mu_ck,
                                                 _Float16* __restrict__ reconT) {
  __shared__ __align__(16) short Az[128 * 64];
  __shared__ __align__(16) short Bm[128 * 64];
  const int tid = threadIdx.x;
  const int l = tid & 63, w = tid >> 6;
  const int wm = w >> 1, wn = w & 1;
  const int lr = l & 15, lh = l >> 4;
  const int n0 = blockIdx.x * 128;
  const int c0 = blockIdx.y * 128;
  const int b = blockIdx.z;
  const short* Ag = (const short*)(z + (size_t)b * NDIM * KDIM);
  const short* Bg = (const short*)(mu_ck + (size_t)b * CDIM * KDIM);
#pragma unroll
  for (int i = 0; i < 4; ++i) {
    int slot = i * 256 + tid;
    int r = slot >> 3, s = slot & 7, sp = s ^ (r & 7);
    g2lds16(Ag + (size_t)(n0 + r) * KDIM + sp * 8, Az + slot * 8);
  }
#pragma unroll
  for (int i = 0; i < 4; ++i) {
    int slot = i * 256 + tid;
    int r = slot >> 3, s = slot & 7, sp = s ^ (r & 7);
    g2lds16(Bg + (size_t)(c0 + r) * KDIM + sp * 8, Bm + slot * 8);
  }
  __syncthreads();
  f32x4 acc[4][4] = {};
#pragma unroll
  for (int kk = 0; kk < 2; ++kk) {
    f16x8 af[4], bf[4];
#pragma unroll
    for (int m = 0; m < 4; ++m) af[m] = ldsfrag(Az, wm * 64 + m * 16 + lr, kk, lh);
#pragma unroll
    for (int nf = 0; nf < 4; ++nf) bf[nf] = ldsfrag(Bm, wn * 64 + nf * 16 + lr, kk, lh);
#pragma unroll
    for (int m = 0; m < 4; ++m)
#pragma unroll
      for (int nf = 0; nf < 4; ++nf)
        acc[m][nf] = __builtin_amdgcn_mfma_f32_16x16x32_f16(af[m], bf[nf],
                                                            acc[m][nf], 0, 0, 0);
  }
  _Float16* ob = reconT + (size_t)b * NDIM * CDIM;
#pragma unroll
  for (int m = 0; m < 4; ++m) {
#pragma unroll
    for (int r = 0; r < 4; ++r) {
      int n = n0 + wm * 64 + m * 16 + lh * 4 + r;
#pragma unroll
      for (int nf = 0; nf < 4; ++nf) {
        int c = c0 + wn * 64 + nf * 16 + lr;
        ob[(size_t)n * CDIM + c] = (_Float16)fmaxf(acc[m][nf][r], 0.f);
      }
    }
  }
}

// ---------------------------------------------------------------------------
// final: out = relu((y-mean)*rsqrt(var+eps)*gamma + beta + x), y fp16
// ---------------------------------------------------------------------------
__global__ void k_final(float* __restrict__ out, const _Float16* __restrict__ y16,
                        const float* __restrict__ x,
                        const float* __restrict__ bnsum,
                        const float* __restrict__ bnsumsq,
                        const float* __restrict__ gamma,
                        const float* __restrict__ beta) {
  const float invM = 1.f / (BDIM * (float)NDIM);
  const size_t total4 = (size_t)BDIM * CDIM * NDIM / 4;
  for (size_t i4 = (size_t)blockIdx.x * 256 + threadIdx.x; i4 < total4;
       i4 += (size_t)gridDim.x * 256) {
    int c = (int)((i4 >> 10) & (CDIM - 1));
    float mean = bnsum[c] * invM;
    float var = bnsumsq[c] * invM - mean * mean;
    float sc = rsqrtf(var + 1e-5f) * gamma[c];
    float sh = beta[c] - mean * sc;
    f16x4 yv = *reinterpret_cast<const f16x4*>(&y16[i4 * 4]);
    float4 xv = reinterpret_cast<const float4*>(x)[i4];
    float4 o;
    o.x = fmaxf(fmaf((float)yv[0], sc, sh) + xv.x, 0.f);
    o.y = fmaxf(fmaf((float)yv[1], sc, sh) + xv.y, 0.f);
    o.z = fmaxf(fmaf((float)yv[2], sc, sh) + xv.z, 0.f);
    o.w = fmaxf(fmaf((float)yv[3], sc, sh) + xv.w, 0.f);
    reinterpret_cast<float4*>(out)[i4] = o;
  }
}

// ---------------------------------------------------------------------------
extern "C" void kernel_launch(void* const* d_in, const int* in_sizes, int n_in,
                              void* d_out, int out_size, void* d_ws,
                              size_t ws_size, hipStream_t stream) {
  const float* x = (const float*)d_in[0];
  const float* mu = (const float*)d_in[1];
  const float* w1 = (const float*)d_in[2];
  const float* b1 = (const float*)d_in[3];
  const float* w2 = (const float*)d_in[4];
  const float* gamma = (const float*)d_in[5];
  const float* beta = (const float*)d_in[6];
  float* out = (float*)d_out;

  // xf dual copies live in d_out until conv2/final overwrite it.
  _Float16* xfT = (_Float16*)d_out;              // [B][N][C]
  _Float16* xf = (_Float16*)d_out + 33554432;    // [B][C][N]

  _Float16* wsH = (_Float16*)d_ws;
  _Float16* xT = wsH;                            // [B][N][C] (reused as reconT)
  _Float16* reconT = wsH;
  _Float16* z = wsH + 33554432;                  // [B][N][K]
  _Float16* zT = z + 4194304;                    // [B][K][N]
  _Float16* muT = zT + 4194304;                  // [B][K][C]
  _Float16* mu_ck = muT + 524288;                // [B][C][K]
  _Float16* w1h = mu_ck + 524288;                // [C][C]
  _Float16* w2h = w1h + 262144;
  float* wsF = (float*)(w2h + 262144);
  float* mupart = wsF;                           // [S][B][K][C] f32
  float* colsum = mupart + 4194304;              // [B][K]
  float* bnsum = colsum + 1024;                  // [C]
  float* bnsumsq = bnsum + 512;                  // [C]
  _Float16* y16 = (_Float16*)(bnsumsq + 512);    // [B][C][N] fp16

  k_cvtT16<<<dim3(NDIM / 64, CDIM / 64, BDIM), 256, 0, stream>>>(x, xT);
  k_cvt_w16<<<CDIM * CDIM / 1024, 256, 0, stream>>>(w1, w1h);
  k_cvt_w16<<<CDIM * CDIM / 1024, 256, 0, stream>>>(w2, w2h);

  k_conv1_16<<<dim3(NDIM / 128, CDIM / 128, BDIM), 256, 0, stream>>>(
      xT, w1h, b1, xfT, xf);
  k_init_mu16<<<2048, 256, 0, stream>>>(mu, muT);

  for (int s = 0; s < 3; ++s) {
    hipMemsetAsync(colsum, 0, 1024 * sizeof(float), stream);
    k_s1_16<<<dim3(NDIM / 128, BDIM), 256, 0, stream>>>(xfT, muT, z, zT, colsum);
    k_s2_16<<<dim3(CDIM / 128, NSPLIT, BDIM), 256, 0, stream>>>(zT, xf, mupart);
    k_s2red<<<KDIM * BDIM, 256, 0, stream>>>(mupart, colsum, muT, mu_ck);
  }

  k_recon16<<<dim3(NDIM / 128, CDIM / 128, BDIM), 256, 0, stream>>>(z, mu_ck,
                                                                    reconT);
  hipMemsetAsync(bnsum, 0, 1024 * sizeof(float), stream);
  k_conv2_16<<<dim3(NDIM / 128, CDIM / 128, BDIM), 256, 0, stream>>>(
      w2h, reconT, y16, bnsum, bnsumsq);

  k_final<<<4096, 256, 0, stream>>>(out, y16, x, bnsum, bnsumsq, gamma, beta);
}